// Round 8
// baseline (3963.875 us; speedup 1.0000x reference)
//
#include <hip/hip_runtime.h>
#include <math.h>

#define G_N 50000
#define D_S 3
#define HC 64
#define IN_DIM 256
#define OUT_DIM 40
#define NL 4
#define NNZV 2400000
#define NN (G_N * D_S)          // 150000
#define SUBROWS 125
#define NSB 1200                // NN / SUBROWS
#define CHUNK 16384
#define NBLK_SCAT 147           // ceil(NNZV / CHUNK)
#define BUF2_CAP 2450000        // padded nnz capacity

typedef __attribute__((ext_vector_type(8))) short bf16x8;
typedef __attribute__((ext_vector_type(4))) float f32x4;

__device__ __forceinline__ float elu_f(float v) {
    return v > 0.0f ? v : expm1f(v);
}

__device__ __forceinline__ unsigned short f2bf(float f) {
    unsigned u = __float_as_uint(f);
    return (unsigned short)((u + 0x7FFF + ((u >> 16) & 1)) >> 16);
}

// ---------------- lin1 via MFMA bf16: h0[g,j] = elu(x@W1^T + b)
__global__ __launch_bounds__(256) void lin1_mfma(const float* __restrict__ x,
        const float* __restrict__ W, const float* __restrict__ b,
        float* __restrict__ out) {
    __shared__ __align__(16) unsigned short Ab[2][64][72];
    __shared__ __align__(16) unsigned short Bb[2][192][72];
    int tid = threadIdx.x;
    int m0 = blockIdx.x * 64;
    int w = tid >> 6, lane = tid & 63;
    int l15 = lane & 15, kg = lane >> 4;

    f32x4 acc[12];
    #pragma unroll
    for (int nb = 0; nb < 12; ++nb) acc[nb] = (f32x4){0.f, 0.f, 0.f, 0.f};

    auto stage = [&](int kt, int bf) {
        int k0 = kt * 64;
        #pragma unroll
        for (int p = 0; p < 4; ++p) {
            int fid = p * 256 + tid;
            int r = fid >> 4, kq = fid & 15;
            int gr = m0 + r;
            float4 v = make_float4(0.f, 0.f, 0.f, 0.f);
            if (gr < G_N) v = *(const float4*)(x + (size_t)gr * IN_DIM + k0 + kq * 4);
            Ab[bf][r][kq*4+0] = f2bf(v.x); Ab[bf][r][kq*4+1] = f2bf(v.y);
            Ab[bf][r][kq*4+2] = f2bf(v.z); Ab[bf][r][kq*4+3] = f2bf(v.w);
        }
        #pragma unroll
        for (int p = 0; p < 12; ++p) {
            int fid = p * 256 + tid;
            int j = fid >> 4, kq = fid & 15;
            float4 v = *(const float4*)(W + (size_t)j * IN_DIM + k0 + kq * 4);
            Bb[bf][j][kq*4+0] = f2bf(v.x); Bb[bf][j][kq*4+1] = f2bf(v.y);
            Bb[bf][j][kq*4+2] = f2bf(v.z); Bb[bf][j][kq*4+3] = f2bf(v.w);
        }
    };

    stage(0, 0);
    __syncthreads();
    int bf = 0;
    for (int kt = 0; kt < 4; ++kt) {
        if (kt < 3) stage(kt + 1, bf ^ 1);
        #pragma unroll
        for (int ks = 0; ks < 2; ++ks) {
            bf16x8 af = *(const bf16x8*)&Ab[bf][w*16 + l15][ks*32 + kg*8];
            #pragma unroll
            for (int nb = 0; nb < 12; ++nb) {
                bf16x8 bv = *(const bf16x8*)&Bb[bf][nb*16 + l15][ks*32 + kg*8];
                acc[nb] = __builtin_amdgcn_mfma_f32_16x16x32_bf16(af, bv, acc[nb], 0, 0, 0);
            }
        }
        __syncthreads();
        bf ^= 1;
    }

    #pragma unroll
    for (int nb = 0; nb < 12; ++nb) {
        float bias = b[nb*16 + l15];
        #pragma unroll
        for (int i = 0; i < 4; ++i) {
            int gr = m0 + w*16 + kg*4 + i;
            if (gr < G_N)
                out[(size_t)gr * 192 + nb*16 + l15] = elu_f(acc[nb][i] + bias);
        }
    }
}

// ---------------- transform via MFMA bf16: tb[n,j] = bf16(sum_c A[n,c]*Wr[j,c])
__global__ __launch_bounds__(256) void transform_mfma(const float* __restrict__ h0,
        const float* __restrict__ lw, const float* __restrict__ Wr,
        unsigned short* __restrict__ tb) {
    __shared__ __align__(16) unsigned short Asb[64][72];
    __shared__ __align__(16) unsigned short Bsb[64][72];
    int tid = threadIdx.x;
    int r0 = blockIdx.x * 64;

    float L[9];
    #pragma unroll
    for (int i = 0; i < 9; ++i) L[i] = lw[i];

    #pragma unroll
    for (int p = 0; p < 16; ++p) {
        int idx = p * 256 + tid;
        Bsb[idx >> 6][idx & 63] = f2bf(Wr[idx]);
    }
    #pragma unroll
    for (int p = 0; p < 16; ++p) {
        int idx = p * 256 + tid;
        int r = idx >> 6, c = idx & 63;
        int gr = r0 + r;
        float m = 0.0f;
        if (gr < NN) {
            int g = gr / 3, e = gr - g * 3;
            const float* base = h0 + (size_t)(g * 3) * HC + c;
            m = L[e*3+0]*base[0] + L[e*3+1]*base[HC] + L[e*3+2]*base[2*HC];
        }
        Asb[r][c] = f2bf(m);
    }
    __syncthreads();

    int w = tid >> 6, lane = tid & 63;
    int l15 = lane & 15, kg = lane >> 4;

    f32x4 acc[4];
    #pragma unroll
    for (int nb = 0; nb < 4; ++nb) acc[nb] = (f32x4){0.f, 0.f, 0.f, 0.f};

    #pragma unroll
    for (int ks = 0; ks < 2; ++ks) {
        bf16x8 af = *(const bf16x8*)&Asb[w*16 + l15][ks*32 + kg*8];
        #pragma unroll
        for (int nb = 0; nb < 4; ++nb) {
            bf16x8 bfv = *(const bf16x8*)&Bsb[nb*16 + l15][ks*32 + kg*8];
            acc[nb] = __builtin_amdgcn_mfma_f32_16x16x32_bf16(af, bfv, acc[nb], 0, 0, 0);
        }
    }

    #pragma unroll
    for (int nb = 0; nb < 4; ++nb) {
        #pragma unroll
        for (int i = 0; i < 4; ++i) {
            int rr = r0 + w*16 + kg*4 + i;
            if (rr < NN) tb[(size_t)rr * HC + nb*16 + l15] = f2bf(acc[nb][i]);
        }
    }
}

// ---------------- sub-bucket build ----------------
// countA: per-chunk LDS hist over 1200 subs -> global scnt
__global__ __launch_bounds__(256) void countA_k(const int* __restrict__ rows,
        int* __restrict__ scnt) {
    __shared__ int cnt[NSB];
    int tid = threadIdx.x;
    for (int i = tid; i < NSB; i += 256) cnt[i] = 0;
    __syncthreads();
    int c0 = blockIdx.x * CHUNK;
    #pragma unroll 4
    for (int it = 0; it < CHUNK / 256; ++it) {
        int i = c0 + it * 256 + tid;
        if (i < NNZV) {
            int r = rows[i];
            atomicAdd(&cnt[r / SUBROWS], 1);
        }
    }
    __syncthreads();
    for (int s = tid; s < NSB; s += 256)
        if (cnt[s]) atomicAdd(&scnt[s], cnt[s]);
}

// scan over 1200 padded-to-16 counts; writes rp2[0..NSB] and gcur (cursor init)
__global__ __launch_bounds__(256) void scan1200_k(const int* __restrict__ scnt,
        int* __restrict__ rp2, int* __restrict__ gcur) {
    __shared__ int bs[256];
    int t = threadIdx.x;
    int v[5]; int sum = 0;
    #pragma unroll
    for (int j = 0; j < 5; ++j) {
        int idx = t * 5 + j;
        int c = (idx < NSB) ? scnt[idx] : 0;
        v[j] = (c + 15) & ~15;
        sum += v[j];
    }
    bs[t] = sum; __syncthreads();
    #pragma unroll
    for (int off = 1; off < 256; off <<= 1) {
        int x = 0;
        if (t >= off) x = bs[t - off];
        __syncthreads();
        if (t >= off) bs[t] += x;
        __syncthreads();
    }
    int run = bs[t] - sum;
    #pragma unroll
    for (int j = 0; j < 5; ++j) {
        int idx = t * 5 + j;
        if (idx < NSB) { rp2[idx] = run; gcur[idx] = run; }
        run += v[j];
    }
    if (t == 255) rp2[NSB] = run;
}

// scatterA: chunk-owned two-pass; block reserves per-sub ranges, writes packed entries
__global__ __launch_bounds__(256) void scatterA_k(const int* __restrict__ rows,
        const int* __restrict__ cols, const float* __restrict__ vals,
        int* __restrict__ gcur, long long* __restrict__ buf2) {
    __shared__ int cnt[NSB];
    __shared__ int base[NSB];
    int tid = threadIdx.x;
    for (int i = tid; i < NSB; i += 256) cnt[i] = 0;
    __syncthreads();
    int c0 = blockIdx.x * CHUNK;
    #pragma unroll 4
    for (int it = 0; it < CHUNK / 256; ++it) {
        int i = c0 + it * 256 + tid;
        if (i < NNZV) atomicAdd(&cnt[rows[i] / SUBROWS], 1);
    }
    __syncthreads();
    for (int s = tid; s < NSB; s += 256) {
        int c = cnt[s];
        if (c) base[s] = atomicAdd(&gcur[s], c);
        cnt[s] = 0;
    }
    __syncthreads();
    #pragma unroll 4
    for (int it = 0; it < CHUNK / 256; ++it) {
        int i = c0 + it * 256 + tid;
        if (i < NNZV) {
            int r = rows[i];                         // L2-hot re-read
            int c = __builtin_nontemporal_load(cols + i);
            float v = __builtin_nontemporal_load(vals + i);
            int s = r / SUBROWS;
            int rloc = r - s * SUBROWS;
            int idx = atomicAdd(&cnt[s], 1);
            long long packed = ((long long)__float_as_int(v) << 32)
                             | (unsigned)((rloc << 18) | c);
            buf2[base[s] + idx] = packed;
        }
    }
}

// ---------------- SpMM over sub-buckets: LDS accumulation + fused epilogue
__global__ __launch_bounds__(256) void spmm_lds(const int* __restrict__ rp2,
        const long long* __restrict__ buf2, const unsigned short* __restrict__ tb,
        float* __restrict__ h0, const float* __restrict__ eps, int l) {
    __shared__ float acc[SUBROWS * HC];   // 32000 B
    int s = blockIdx.x;
    int tid = threadIdx.x;
    int wv = tid >> 6, lane = tid & 63;
    for (int i = tid; i < SUBROWS * HC; i += 256) acc[i] = 0.0f;
    __syncthreads();
    int o = rp2[s], e = rp2[s + 1];       // length multiple of 16 (pads are zero entries)
    for (int cb = o + wv * 64; cb < e; cb += 256) {
        int rem = e - cb;
        int n = rem > 64 ? 64 : rem;      // multiple of 16
        long long packed = 0;
        if (lane < n) packed = __builtin_nontemporal_load(buf2 + cb + lane);
        int plo = (int)packed;
        int phi = (int)(packed >> 32);
        for (int j0 = 0; j0 < n; j0 += 16) {
            float hv[16], vv[16]; int rl[16];
            #pragma unroll
            for (int u = 0; u < 16; ++u) {
                int lo = __shfl(plo, j0 + u);
                vv[u] = __int_as_float(__shfl(phi, j0 + u));
                int c = lo & 0x3FFFF;
                rl[u] = lo >> 18;
                hv[u] = __uint_as_float((unsigned)tb[(size_t)c * HC + lane] << 16);
            }
            #pragma unroll
            for (int u = 0; u < 16; ++u)
                atomicAdd(&acc[rl[u] * HC + lane], vv[u] * hv[u]);
        }
    }
    __syncthreads();
    // epilogue: h0 = gate*h0 - elu(acc)
    float g3[3];
    #pragma unroll
    for (int d = 0; d < 3; ++d) g3[d] = 1.0f + tanhf(eps[l * 3 + d]);
    int lo_row = s * SUBROWS;
    for (int r = wv; r < SUBROWS; r += 4) {
        int gr = lo_row + r;
        float a = acc[r * HC + lane];
        float hnew = a > 0.0f ? a : expm1f(a);
        size_t idx = (size_t)gr * HC + lane;
        float h0v = __builtin_nontemporal_load(h0 + idx);
        __builtin_nontemporal_store(g3[gr % 3] * h0v - hnew, h0 + idx);
    }
}

// ---------------- lin2 (tiled GEMM, N padded 40->64) + fused log_softmax
__global__ __launch_bounds__(256) void lin2_ls_gemm(const float* __restrict__ h,
        const float* __restrict__ W, const float* __restrict__ b,
        float* __restrict__ out) {
    const int K = 192;
    __shared__ float As[32][65];
    __shared__ float Bs[32][65];
    int tid = threadIdx.x;
    int tx = tid & 15, ty = tid >> 4;
    int m0 = blockIdx.x * 64;

    float acc[4][4] = {};
    int kslot = tid & 7;
    int row   = tid >> 3;

    for (int k0 = 0; k0 < K; k0 += 32) {
        #pragma unroll
        for (int pass = 0; pass < 2; ++pass) {
            int r = row + pass * 32;
            int gr = m0 + r;
            float4 v = make_float4(0.f, 0.f, 0.f, 0.f);
            if (gr < G_N) v = *(const float4*)(h + (size_t)gr * K + k0 + kslot * 4);
            As[kslot*4+0][r] = v.x; As[kslot*4+1][r] = v.y;
            As[kslot*4+2][r] = v.z; As[kslot*4+3][r] = v.w;

            int j = r;
            float4 w4 = make_float4(0.f, 0.f, 0.f, 0.f);
            if (j < OUT_DIM) w4 = *(const float4*)(W + (size_t)j * K + k0 + kslot * 4);
            Bs[kslot*4+0][j] = w4.x; Bs[kslot*4+1][j] = w4.y;
            Bs[kslot*4+2][j] = w4.z; Bs[kslot*4+3][j] = w4.w;
        }
        __syncthreads();
        #pragma unroll 8
        for (int k = 0; k < 32; ++k) {
            float4 a4 = *(const float4*)&As[k][ty*4];
            float4 b4 = *(const float4*)&Bs[k][tx*4];
            float av[4] = {a4.x, a4.y, a4.z, a4.w};
            float bv[4] = {b4.x, b4.y, b4.z, b4.w};
            #pragma unroll
            for (int i = 0; i < 4; ++i)
                #pragma unroll
                for (int j = 0; j < 4; ++j)
                    acc[i][j] = fmaf(av[i], bv[j], acc[i][j]);
        }
        __syncthreads();
    }

    bool validc = (tx < 10);
    float bi[4];
    #pragma unroll
    for (int j = 0; j < 4; ++j) bi[j] = validc ? b[tx*4+j] : 0.0f;

    #pragma unroll
    for (int i = 0; i < 4; ++i) {
        int gr = m0 + ty*4 + i;
        float v[4];
        float mymax = -INFINITY;
        #pragma unroll
        for (int j = 0; j < 4; ++j) {
            v[j] = acc[i][j] + bi[j];
            if (validc) mymax = fmaxf(mymax, v[j]);
        }
        #pragma unroll
        for (int off = 1; off < 16; off <<= 1) mymax = fmaxf(mymax, __shfl_xor(mymax, off));
        float s = 0.0f;
        if (validc) {
            #pragma unroll
            for (int j = 0; j < 4; ++j) s += expf(v[j] - mymax);
        }
        #pragma unroll
        for (int off = 1; off < 16; off <<= 1) s += __shfl_xor(s, off);
        float lse = mymax + logf(s);
        if (gr < G_N && validc) {
            float4 o = make_float4(v[0]-lse, v[1]-lse, v[2]-lse, v[3]-lse);
            *(float4*)(out + (size_t)gr * OUT_DIM + tx*4) = o;
        }
    }
}

extern "C" void kernel_launch(void* const* d_in, const int* in_sizes, int n_in,
                              void* d_out, int out_size, void* d_ws, size_t ws_size,
                              hipStream_t stream) {
    const float* x      = (const float*)d_in[0];
    const int*   rows   = (const int*)d_in[1];
    const int*   cols   = (const int*)d_in[2];
    const float* vals   = (const float*)d_in[3];
    const float* lin1_w = (const float*)d_in[4];
    const float* lin1_b = (const float*)d_in[5];
    const float* left_w = (const float*)d_in[6];
    const float* right_w= (const float*)d_in[7];
    const float* eps    = (const float*)d_in[8];
    const float* lin2_w = (const float*)d_in[9];
    const float* lin2_b = (const float*)d_in[10];
    float* out = (float*)d_out;

    size_t bufElems = (size_t)NN * HC;                     // 9.6M
    float* h0 = (float*)d_ws;                              // 38.4 MB
    unsigned short* tb = (unsigned short*)(h0 + bufElems); // 19.2 MB
    int* rp2  = (int*)(tb + bufElems);                     // NSB+1
    int* gcur = rp2 + 1204;                                // NSB
    int* scnt = gcur + 1200;                               // NSB
    long long* buf2 = (long long*)(scnt + 1200 + 28);      // 8B-aligned; 19.6 MB

    dim3 b256(256);

    // --- sub-bucket CSR-lite build (once; reused by all 4 layers) ---
    hipMemsetAsync(scnt, 0, NSB * sizeof(int), stream);
    hipMemsetAsync(buf2, 0, (size_t)BUF2_CAP * sizeof(long long), stream);
    countA_k<<<dim3(NBLK_SCAT), b256, 0, stream>>>(rows, scnt);
    scan1200_k<<<dim3(1), b256, 0, stream>>>(scnt, rp2, gcur);
    scatterA_k<<<dim3(NBLK_SCAT), b256, 0, stream>>>(rows, cols, vals, gcur, buf2);

    // --- lin1 -> h0 (MFMA bf16) ---
    lin1_mfma<<<dim3((G_N + 63) / 64), b256, 0, stream>>>(x, lin1_w, lin1_b, h0);

    for (int l = 0; l < NL; ++l) {
        transform_mfma<<<dim3((NN + 63) / 64), b256, 0, stream>>>(
            h0, left_w + l * 9, right_w + l * HC * HC, tb);
        spmm_lds<<<dim3(NSB), b256, 0, stream>>>(rp2, buf2, tb, h0, eps, l);
    }

    lin2_ls_gemm<<<dim3((G_N + 63) / 64), b256, 0, stream>>>(h0, lin2_w, lin2_b, out);
}

// Round 9
// 607.074 us; speedup vs baseline: 6.5295x; 6.5295x over previous
//
#include <hip/hip_runtime.h>
#include <math.h>

#define G_N 50000
#define D_S 3
#define HC 64
#define IN_DIM 256
#define OUT_DIM 40
#define NL 4
#define NNZV 2400000
#define NN (G_N * D_S)          // 150000
#define SUBROWS 125
#define NSB 1200                // NN / SUBROWS
#define CHUNK 16384
#define NBLK_SCAT 147           // ceil(NNZV / CHUNK)
#define BWIN 2560               // buf2 window per sub (mean 2000, +12 sigma)
#define PSUB 4608               // padded pcv window per sub (mean ~2940)

typedef __attribute__((ext_vector_type(8))) short bf16x8;
typedef __attribute__((ext_vector_type(4))) float f32x4;

__device__ __forceinline__ float elu_f(float v) {
    return v > 0.0f ? v : expm1f(v);
}

__device__ __forceinline__ unsigned short f2bf(float f) {
    unsigned u = __float_as_uint(f);
    return (unsigned short)((u + 0x7FFF + ((u >> 16) & 1)) >> 16);
}

// ---------------- lin1 via MFMA bf16: h0[g,j] = elu(x@W1^T + b)
__global__ __launch_bounds__(256) void lin1_mfma(const float* __restrict__ x,
        const float* __restrict__ W, const float* __restrict__ b,
        float* __restrict__ out) {
    __shared__ __align__(16) unsigned short Ab[2][64][72];
    __shared__ __align__(16) unsigned short Bb[2][192][72];
    int tid = threadIdx.x;
    int m0 = blockIdx.x * 64;
    int w = tid >> 6, lane = tid & 63;
    int l15 = lane & 15, kg = lane >> 4;

    f32x4 acc[12];
    #pragma unroll
    for (int nb = 0; nb < 12; ++nb) acc[nb] = (f32x4){0.f, 0.f, 0.f, 0.f};

    auto stage = [&](int kt, int bf) {
        int k0 = kt * 64;
        #pragma unroll
        for (int p = 0; p < 4; ++p) {
            int fid = p * 256 + tid;
            int r = fid >> 4, kq = fid & 15;
            int gr = m0 + r;
            float4 v = make_float4(0.f, 0.f, 0.f, 0.f);
            if (gr < G_N) v = *(const float4*)(x + (size_t)gr * IN_DIM + k0 + kq * 4);
            Ab[bf][r][kq*4+0] = f2bf(v.x); Ab[bf][r][kq*4+1] = f2bf(v.y);
            Ab[bf][r][kq*4+2] = f2bf(v.z); Ab[bf][r][kq*4+3] = f2bf(v.w);
        }
        #pragma unroll
        for (int p = 0; p < 12; ++p) {
            int fid = p * 256 + tid;
            int j = fid >> 4, kq = fid & 15;
            float4 v = *(const float4*)(W + (size_t)j * IN_DIM + k0 + kq * 4);
            Bb[bf][j][kq*4+0] = f2bf(v.x); Bb[bf][j][kq*4+1] = f2bf(v.y);
            Bb[bf][j][kq*4+2] = f2bf(v.z); Bb[bf][j][kq*4+3] = f2bf(v.w);
        }
    };

    stage(0, 0);
    __syncthreads();
    int bf = 0;
    for (int kt = 0; kt < 4; ++kt) {
        if (kt < 3) stage(kt + 1, bf ^ 1);
        #pragma unroll
        for (int ks = 0; ks < 2; ++ks) {
            bf16x8 af = *(const bf16x8*)&Ab[bf][w*16 + l15][ks*32 + kg*8];
            #pragma unroll
            for (int nb = 0; nb < 12; ++nb) {
                bf16x8 bv = *(const bf16x8*)&Bb[bf][nb*16 + l15][ks*32 + kg*8];
                acc[nb] = __builtin_amdgcn_mfma_f32_16x16x32_bf16(af, bv, acc[nb], 0, 0, 0);
            }
        }
        __syncthreads();
        bf ^= 1;
    }

    // D layout: col = lane&15, row = (lane>>4)*4 + reg
    #pragma unroll
    for (int nb = 0; nb < 12; ++nb) {
        float bias = b[nb*16 + l15];
        #pragma unroll
        for (int i = 0; i < 4; ++i) {
            int gr = m0 + w*16 + kg*4 + i;
            if (gr < G_N)
                out[(size_t)gr * 192 + nb*16 + l15] = elu_f(acc[nb][i] + bias);
        }
    }
}

// ---------------- transform via MFMA bf16: tb[n,j] = bf16(sum_c A[n,c]*Wr[j,c])
__global__ __launch_bounds__(256) void transform_mfma(const float* __restrict__ h0,
        const float* __restrict__ lw, const float* __restrict__ Wr,
        unsigned short* __restrict__ tb) {
    __shared__ __align__(16) unsigned short Asb[64][72];
    __shared__ __align__(16) unsigned short Bsb[64][72];
    int tid = threadIdx.x;
    int r0 = blockIdx.x * 64;

    float L[9];
    #pragma unroll
    for (int i = 0; i < 9; ++i) L[i] = lw[i];

    #pragma unroll
    for (int p = 0; p < 16; ++p) {
        int idx = p * 256 + tid;
        Bsb[idx >> 6][idx & 63] = f2bf(Wr[idx]);
    }
    #pragma unroll
    for (int p = 0; p < 16; ++p) {
        int idx = p * 256 + tid;
        int r = idx >> 6, c = idx & 63;
        int gr = r0 + r;
        float m = 0.0f;
        if (gr < NN) {
            int g = gr / 3, e = gr - g * 3;
            const float* base = h0 + (size_t)(g * 3) * HC + c;
            m = L[e*3+0]*base[0] + L[e*3+1]*base[HC] + L[e*3+2]*base[2*HC];
        }
        Asb[r][c] = f2bf(m);
    }
    __syncthreads();

    int w = tid >> 6, lane = tid & 63;
    int l15 = lane & 15, kg = lane >> 4;

    f32x4 acc[4];
    #pragma unroll
    for (int nb = 0; nb < 4; ++nb) acc[nb] = (f32x4){0.f, 0.f, 0.f, 0.f};

    #pragma unroll
    for (int ks = 0; ks < 2; ++ks) {
        bf16x8 af = *(const bf16x8*)&Asb[w*16 + l15][ks*32 + kg*8];
        #pragma unroll
        for (int nb = 0; nb < 4; ++nb) {
            bf16x8 bfv = *(const bf16x8*)&Bsb[nb*16 + l15][ks*32 + kg*8];
            acc[nb] = __builtin_amdgcn_mfma_f32_16x16x32_bf16(af, bfv, acc[nb], 0, 0, 0);
        }
    }

    #pragma unroll
    for (int nb = 0; nb < 4; ++nb) {
        #pragma unroll
        for (int i = 0; i < 4; ++i) {
            int rr = r0 + w*16 + kg*4 + i;
            if (rr < NN) tb[(size_t)rr * HC + nb*16 + l15] = f2bf(acc[nb][i]);
        }
    }
}

// ---------------- build step 0: init per-sub cursors to fixed windows
__global__ __launch_bounds__(256) void init_cur_k(int* __restrict__ gcur) {
    int i = blockIdx.x * 256 + threadIdx.x;
    if (i < NSB) gcur[i] = i * BWIN;
}

// ---------------- build step 1: partition COO into fixed per-sub windows (~100B write runs)
__global__ __launch_bounds__(256) void scatterA_k(const int* __restrict__ rows,
        const int* __restrict__ cols, const float* __restrict__ vals,
        int* __restrict__ gcur, long long* __restrict__ buf2) {
    __shared__ int cnt[NSB];
    __shared__ int base[NSB];
    int tid = threadIdx.x;
    for (int i = tid; i < NSB; i += 256) cnt[i] = 0;
    __syncthreads();
    int c0 = blockIdx.x * CHUNK;
    #pragma unroll 4
    for (int it = 0; it < CHUNK / 256; ++it) {
        int i = c0 + it * 256 + tid;
        if (i < NNZV) atomicAdd(&cnt[rows[i] / SUBROWS], 1);
    }
    __syncthreads();
    for (int s = tid; s < NSB; s += 256) {
        int c = cnt[s];
        if (c) base[s] = atomicAdd(&gcur[s], c);
        cnt[s] = 0;
    }
    __syncthreads();
    #pragma unroll 4
    for (int it = 0; it < CHUNK / 256; ++it) {
        int i = c0 + it * 256 + tid;
        if (i < NNZV) {
            int r = rows[i];                         // L2-hot re-read
            int c = __builtin_nontemporal_load(cols + i);
            float v = __builtin_nontemporal_load(vals + i);
            int s = r / SUBROWS;
            int rloc = r - s * SUBROWS;
            int idx = atomicAdd(&cnt[s], 1);
            long long packed = ((long long)__float_as_int(v) << 32)
                             | (unsigned)((rloc << 18) | c);
            buf2[base[s] + idx] = packed;
        }
    }
}

// ---------------- build step 2: per-sub LDS sort -> row-contiguous padded CSR + rs/re
__global__ __launch_bounds__(256) void sortB_k(const long long* __restrict__ buf2,
        const int* __restrict__ gcur, long long* __restrict__ pcv,
        int* __restrict__ rs, int* __restrict__ re) {
    __shared__ long long ent[BWIN];       // 20.5 KB
    __shared__ int cnt[SUBROWS];
    __shared__ int off[SUBROWS];
    __shared__ int scanbuf[128];
    int s = blockIdx.x;
    int tid = threadIdx.x;
    int bb = s * BWIN;
    int n = gcur[s] - bb;

    for (int i = tid; i < n; i += 256) ent[i] = buf2[bb + i];
    for (int i = tid; i < SUBROWS; i += 256) cnt[i] = 0;
    __syncthreads();
    for (int i = tid; i < n; i += 256) {
        int rl = ((int)ent[i]) >> 18;     // rloc (col is 18 bits, rloc<<18 < 2^25)
        atomicAdd(&cnt[rl], 1);
    }
    __syncthreads();
    // exclusive scan of padded (to 16) counts over 125 rows
    int pc = 0;
    if (tid < 128) {
        int c = (tid < SUBROWS) ? cnt[tid] : 0;
        pc = (c + 15) & ~15;
        scanbuf[tid] = pc;
    }
    __syncthreads();
    for (int o = 1; o < 128; o <<= 1) {
        int x = 0;
        if (tid < 128 && tid >= o) x = scanbuf[tid - o];
        __syncthreads();
        if (tid < 128 && tid >= o) scanbuf[tid] += x;
        __syncthreads();
    }
    if (tid < SUBROWS) { off[tid] = scanbuf[tid] - pc; cnt[tid] = scanbuf[tid] - pc; }
    __syncthreads();
    // scatter within the sub's private pcv window (write-amp ~1)
    long long* outp = pcv + (size_t)s * PSUB;
    for (int i = tid; i < n; i += 256) {
        long long e = ent[i];
        int rl = ((int)e) >> 18;
        int p = atomicAdd(&cnt[rl], 1);
        outp[p] = e;
    }
    __syncthreads();
    // zero row-pad slots, write row bounds
    if (tid < SUBROWS) {
        int st = off[tid];
        int en = cnt[tid];                       // st + real count
        int gend = st + ((en - st + 15) & ~15);  // st + padded count
        for (int p = en; p < gend; ++p) outp[p] = 0;
        int gr = s * SUBROWS + tid;
        rs[gr] = s * PSUB + st;
        re[gr] = s * PSUB + gend;
    }
}

// ---------------- fused padded-CSR SpMM + elu + gated residual: h0 = gate*h0 - elu(L@t)
__global__ __launch_bounds__(256) void spmm_csr_fused(const int* __restrict__ rs,
        const int* __restrict__ re, const long long* __restrict__ pcv,
        const unsigned short* __restrict__ tb,
        float* __restrict__ h0, const float* __restrict__ eps, int l) {
    int w = blockIdx.x * 4 + (threadIdx.x >> 6);
    int lane = threadIdx.x & 63;
    if (w >= NN) return;
    int s = rs[w], e = re[w];                // e-s is a multiple of 16
    float acc = 0.0f;
    for (int cb = s; cb < e; cb += 64) {
        int n = e - cb; if (n > 64) n = 64;  // multiple of 16
        long long packed = 0;
        if (lane < n) packed = __builtin_nontemporal_load(pcv + cb + lane);
        int cvx = (int)packed;               // (rloc<<18)|col
        int cvy = (int)(packed >> 32);       // val bits
        for (int j0 = 0; j0 < n; j0 += 16) {
            float hv[16], vv[16];
            #pragma unroll
            for (int u = 0; u < 16; ++u) {
                int   c = __shfl(cvx, j0 + u) & 0x3FFFF;
                vv[u]   = __int_as_float(__shfl(cvy, j0 + u));
                hv[u]   = __uint_as_float((unsigned)tb[(size_t)c * HC + lane] << 16);
            }
            #pragma unroll
            for (int u = 0; u < 16; ++u) acc = fmaf(vv[u], hv[u], acc);
        }
    }
    float hnew = acc > 0.0f ? acc : expm1f(acc);
    int d = w % 3;
    float gate = 1.0f + tanhf(eps[l * 3 + d]);
    size_t idx = (size_t)w * HC + lane;
    float h0v = __builtin_nontemporal_load(h0 + idx);
    __builtin_nontemporal_store(gate * h0v - hnew, h0 + idx);
}

// ---------------- lin2 (tiled GEMM, N padded 40->64) + fused log_softmax
__global__ __launch_bounds__(256) void lin2_ls_gemm(const float* __restrict__ h,
        const float* __restrict__ W, const float* __restrict__ b,
        float* __restrict__ out) {
    const int K = 192;
    __shared__ float As[32][65];
    __shared__ float Bs[32][65];
    int tid = threadIdx.x;
    int tx = tid & 15, ty = tid >> 4;
    int m0 = blockIdx.x * 64;

    float acc[4][4] = {};
    int kslot = tid & 7;
    int row   = tid >> 3;

    for (int k0 = 0; k0 < K; k0 += 32) {
        #pragma unroll
        for (int pass = 0; pass < 2; ++pass) {
            int r = row + pass * 32;
            int gr = m0 + r;
            float4 v = make_float4(0.f, 0.f, 0.f, 0.f);
            if (gr < G_N) v = *(const float4*)(h + (size_t)gr * K + k0 + kslot * 4);
            As[kslot*4+0][r] = v.x; As[kslot*4+1][r] = v.y;
            As[kslot*4+2][r] = v.z; As[kslot*4+3][r] = v.w;

            int j = r;
            float4 w4 = make_float4(0.f, 0.f, 0.f, 0.f);
            if (j < OUT_DIM) w4 = *(const float4*)(W + (size_t)j * K + k0 + kslot * 4);
            Bs[kslot*4+0][j] = w4.x; Bs[kslot*4+1][j] = w4.y;
            Bs[kslot*4+2][j] = w4.z; Bs[kslot*4+3][j] = w4.w;
        }
        __syncthreads();
        #pragma unroll 8
        for (int k = 0; k < 32; ++k) {
            float4 a4 = *(const float4*)&As[k][ty*4];
            float4 b4 = *(const float4*)&Bs[k][tx*4];
            float av[4] = {a4.x, a4.y, a4.z, a4.w};
            float bv[4] = {b4.x, b4.y, b4.z, b4.w};
            #pragma unroll
            for (int i = 0; i < 4; ++i)
                #pragma unroll
                for (int j = 0; j < 4; ++j)
                    acc[i][j] = fmaf(av[i], bv[j], acc[i][j]);
        }
        __syncthreads();
    }

    bool validc = (tx < 10);
    float bi[4];
    #pragma unroll
    for (int j = 0; j < 4; ++j) bi[j] = validc ? b[tx*4+j] : 0.0f;

    #pragma unroll
    for (int i = 0; i < 4; ++i) {
        int gr = m0 + ty*4 + i;
        float v[4];
        float mymax = -INFINITY;
        #pragma unroll
        for (int j = 0; j < 4; ++j) {
            v[j] = acc[i][j] + bi[j];
            if (validc) mymax = fmaxf(mymax, v[j]);
        }
        #pragma unroll
        for (int off = 1; off < 16; off <<= 1) mymax = fmaxf(mymax, __shfl_xor(mymax, off));
        float s = 0.0f;
        if (validc) {
            #pragma unroll
            for (int j = 0; j < 4; ++j) s += expf(v[j] - mymax);
        }
        #pragma unroll
        for (int off = 1; off < 16; off <<= 1) s += __shfl_xor(s, off);
        float lse = mymax + logf(s);
        if (gr < G_N && validc) {
            float4 o = make_float4(v[0]-lse, v[1]-lse, v[2]-lse, v[3]-lse);
            *(float4*)(out + (size_t)gr * OUT_DIM + tx*4) = o;
        }
    }
}

extern "C" void kernel_launch(void* const* d_in, const int* in_sizes, int n_in,
                              void* d_out, int out_size, void* d_ws, size_t ws_size,
                              hipStream_t stream) {
    const float* x      = (const float*)d_in[0];
    const int*   rows   = (const int*)d_in[1];
    const int*   cols   = (const int*)d_in[2];
    const float* vals   = (const float*)d_in[3];
    const float* lin1_w = (const float*)d_in[4];
    const float* lin1_b = (const float*)d_in[5];
    const float* left_w = (const float*)d_in[6];
    const float* right_w= (const float*)d_in[7];
    const float* eps    = (const float*)d_in[8];
    const float* lin2_w = (const float*)d_in[9];
    const float* lin2_b = (const float*)d_in[10];
    float* out = (float*)d_out;

    size_t bufElems = (size_t)NN * HC;                     // 9.6M
    float* h0 = (float*)d_ws;                              // 38.4 MB
    unsigned short* tb = (unsigned short*)(h0 + bufElems); // 19.2 MB
    long long* pcv = (long long*)(tb + bufElems);          // NSB*PSUB*8 = 44.2 MB
    int* rs   = (int*)(pcv + (size_t)NSB * PSUB);          // 150016
    int* re   = rs + 150016;                               // 150016
    int* gcur = re + 150016;                               // NSB

    // buf2 aliases h0/tb region (fully consumed before lin1 writes h0)
    long long* buf2 = (long long*)d_ws;                    // NSB*BWIN*8 = 24.6 MB

    dim3 b256(256);

    // --- sub-bucketed build (no memsets, no global scans; reused by all 4 layers) ---
    init_cur_k<<<dim3((NSB + 255) / 256), b256, 0, stream>>>(gcur);
    scatterA_k<<<dim3(NBLK_SCAT), b256, 0, stream>>>(rows, cols, vals, gcur, buf2);
    sortB_k<<<dim3(NSB), b256, 0, stream>>>(buf2, gcur, pcv, rs, re);

    // --- lin1 -> h0 (MFMA bf16) ---
    lin1_mfma<<<dim3((G_N + 63) / 64), b256, 0, stream>>>(x, lin1_w, lin1_b, h0);

    for (int l = 0; l < NL; ++l) {
        transform_mfma<<<dim3((NN + 63) / 64), b256, 0, stream>>>(
            h0, left_w + l * 9, right_w + l * HC * HC, tb);
        spmm_csr_fused<<<dim3((NN + 3) / 4), b256, 0, stream>>>(
            rs, re, pcv, tb, h0, eps, l);
    }

    lin2_ls_gemm<<<dim3((G_N + 63) / 64), b256, 0, stream>>>(h0, lin2_w, lin2_b, out);
}

// Round 10
// 605.705 us; speedup vs baseline: 6.5442x; 1.0023x over previous
//
#include <hip/hip_runtime.h>
#include <math.h>

#define G_N 50000
#define D_S 3
#define HC 64
#define IN_DIM 256
#define OUT_DIM 40
#define NL 4
#define NNZV 2400000
#define NN (G_N * D_S)          // 150000
#define SUBROWS 125
#define NSB 1200                // NN / SUBROWS
#define CHUNK 16384
#define NBLK_SCAT 147           // ceil(NNZV / CHUNK)
#define BWIN 2560               // buf2 window per sub (mean 2000, +12 sigma)
#define PSUB 4608               // padded pcv window per sub (mean ~2940)

typedef __attribute__((ext_vector_type(8))) short bf16x8;
typedef __attribute__((ext_vector_type(4))) float f32x4;

__device__ __forceinline__ float elu_f(float v) {
    return v > 0.0f ? v : expm1f(v);
}

__device__ __forceinline__ unsigned short f2bf(float f) {
    unsigned u = __float_as_uint(f);
    return (unsigned short)((u + 0x7FFF + ((u >> 16) & 1)) >> 16);
}

// ---------------- lin1 via MFMA bf16: h0[g,j] = elu(x@W1^T + b)
__global__ __launch_bounds__(256) void lin1_mfma(const float* __restrict__ x,
        const float* __restrict__ W, const float* __restrict__ b,
        float* __restrict__ out) {
    __shared__ __align__(16) unsigned short Ab[2][64][72];
    __shared__ __align__(16) unsigned short Bb[2][192][72];
    int tid = threadIdx.x;
    int m0 = blockIdx.x * 64;
    int w = tid >> 6, lane = tid & 63;
    int l15 = lane & 15, kg = lane >> 4;

    f32x4 acc[12];
    #pragma unroll
    for (int nb = 0; nb < 12; ++nb) acc[nb] = (f32x4){0.f, 0.f, 0.f, 0.f};

    auto stage = [&](int kt, int bf) {
        int k0 = kt * 64;
        #pragma unroll
        for (int p = 0; p < 4; ++p) {
            int fid = p * 256 + tid;
            int r = fid >> 4, kq = fid & 15;
            int gr = m0 + r;
            float4 v = make_float4(0.f, 0.f, 0.f, 0.f);
            if (gr < G_N) v = *(const float4*)(x + (size_t)gr * IN_DIM + k0 + kq * 4);
            Ab[bf][r][kq*4+0] = f2bf(v.x); Ab[bf][r][kq*4+1] = f2bf(v.y);
            Ab[bf][r][kq*4+2] = f2bf(v.z); Ab[bf][r][kq*4+3] = f2bf(v.w);
        }
        #pragma unroll
        for (int p = 0; p < 12; ++p) {
            int fid = p * 256 + tid;
            int j = fid >> 4, kq = fid & 15;
            float4 v = *(const float4*)(W + (size_t)j * IN_DIM + k0 + kq * 4);
            Bb[bf][j][kq*4+0] = f2bf(v.x); Bb[bf][j][kq*4+1] = f2bf(v.y);
            Bb[bf][j][kq*4+2] = f2bf(v.z); Bb[bf][j][kq*4+3] = f2bf(v.w);
        }
    };

    stage(0, 0);
    __syncthreads();
    int bf = 0;
    for (int kt = 0; kt < 4; ++kt) {
        if (kt < 3) stage(kt + 1, bf ^ 1);
        #pragma unroll
        for (int ks = 0; ks < 2; ++ks) {
            bf16x8 af = *(const bf16x8*)&Ab[bf][w*16 + l15][ks*32 + kg*8];
            #pragma unroll
            for (int nb = 0; nb < 12; ++nb) {
                bf16x8 bv = *(const bf16x8*)&Bb[bf][nb*16 + l15][ks*32 + kg*8];
                acc[nb] = __builtin_amdgcn_mfma_f32_16x16x32_bf16(af, bv, acc[nb], 0, 0, 0);
            }
        }
        __syncthreads();
        bf ^= 1;
    }

    // D layout: col = lane&15, row = (lane>>4)*4 + reg
    #pragma unroll
    for (int nb = 0; nb < 12; ++nb) {
        float bias = b[nb*16 + l15];
        #pragma unroll
        for (int i = 0; i < 4; ++i) {
            int gr = m0 + w*16 + kg*4 + i;
            if (gr < G_N)
                out[(size_t)gr * 192 + nb*16 + l15] = elu_f(acc[nb][i] + bias);
        }
    }
}

// ---------------- transform via MFMA bf16: tb[n,j] = bf16(sum_c A[n,c]*Wr[j,c])
__global__ __launch_bounds__(256) void transform_mfma(const float* __restrict__ h0,
        const float* __restrict__ lw, const float* __restrict__ Wr,
        unsigned short* __restrict__ tb) {
    __shared__ __align__(16) unsigned short Asb[64][72];
    __shared__ __align__(16) unsigned short Bsb[64][72];
    int tid = threadIdx.x;
    int r0 = blockIdx.x * 64;

    float L[9];
    #pragma unroll
    for (int i = 0; i < 9; ++i) L[i] = lw[i];

    #pragma unroll
    for (int p = 0; p < 16; ++p) {
        int idx = p * 256 + tid;
        Bsb[idx >> 6][idx & 63] = f2bf(Wr[idx]);
    }
    #pragma unroll
    for (int p = 0; p < 16; ++p) {
        int idx = p * 256 + tid;
        int r = idx >> 6, c = idx & 63;
        int gr = r0 + r;
        float m = 0.0f;
        if (gr < NN) {
            int g = gr / 3, e = gr - g * 3;
            const float* base = h0 + (size_t)(g * 3) * HC + c;
            m = L[e*3+0]*base[0] + L[e*3+1]*base[HC] + L[e*3+2]*base[2*HC];
        }
        Asb[r][c] = f2bf(m);
    }
    __syncthreads();

    int w = tid >> 6, lane = tid & 63;
    int l15 = lane & 15, kg = lane >> 4;

    f32x4 acc[4];
    #pragma unroll
    for (int nb = 0; nb < 4; ++nb) acc[nb] = (f32x4){0.f, 0.f, 0.f, 0.f};

    #pragma unroll
    for (int ks = 0; ks < 2; ++ks) {
        bf16x8 af = *(const bf16x8*)&Asb[w*16 + l15][ks*32 + kg*8];
        #pragma unroll
        for (int nb = 0; nb < 4; ++nb) {
            bf16x8 bfv = *(const bf16x8*)&Bsb[nb*16 + l15][ks*32 + kg*8];
            acc[nb] = __builtin_amdgcn_mfma_f32_16x16x32_bf16(af, bfv, acc[nb], 0, 0, 0);
        }
    }

    #pragma unroll
    for (int nb = 0; nb < 4; ++nb) {
        #pragma unroll
        for (int i = 0; i < 4; ++i) {
            int rr = r0 + w*16 + kg*4 + i;
            if (rr < NN) tb[(size_t)rr * HC + nb*16 + l15] = f2bf(acc[nb][i]);
        }
    }
}

// ---------------- build step 0: init per-sub cursors to fixed windows
__global__ __launch_bounds__(256) void init_cur_k(int* __restrict__ gcur) {
    int i = blockIdx.x * 256 + threadIdx.x;
    if (i < NSB) gcur[i] = i * BWIN;
}

// ---------------- build step 1: partition COO into fixed per-sub windows
// 1024 threads/block: 16 waves -> enough TLP to hide load/atomic latency
__global__ __launch_bounds__(1024) void scatterA_k(const int* __restrict__ rows,
        const int* __restrict__ cols, const float* __restrict__ vals,
        int* __restrict__ gcur, long long* __restrict__ buf2) {
    __shared__ int cnt[NSB];
    __shared__ int base[NSB];
    int tid = threadIdx.x;
    for (int i = tid; i < NSB; i += 1024) cnt[i] = 0;
    __syncthreads();
    int c0 = blockIdx.x * CHUNK;
    #pragma unroll 4
    for (int it = 0; it < CHUNK / 1024; ++it) {
        int i = c0 + it * 1024 + tid;
        if (i < NNZV) atomicAdd(&cnt[rows[i] / SUBROWS], 1);
    }
    __syncthreads();
    for (int s = tid; s < NSB; s += 1024) {
        int c = cnt[s];
        if (c) base[s] = atomicAdd(&gcur[s], c);
        cnt[s] = 0;
    }
    __syncthreads();
    #pragma unroll 4
    for (int it = 0; it < CHUNK / 1024; ++it) {
        int i = c0 + it * 1024 + tid;
        if (i < NNZV) {
            int r = rows[i];                         // L2-hot re-read
            int c = __builtin_nontemporal_load(cols + i);
            float v = __builtin_nontemporal_load(vals + i);
            int s = r / SUBROWS;
            int rloc = r - s * SUBROWS;
            int idx = atomicAdd(&cnt[s], 1);
            long long packed = ((long long)__float_as_int(v) << 32)
                             | (unsigned)((rloc << 18) | c);
            buf2[base[s] + idx] = packed;
        }
    }
}

// ---------------- build step 2: per-sub LDS sort -> row-contiguous padded CSR + rs/re
__global__ __launch_bounds__(256) void sortB_k(const long long* __restrict__ buf2,
        const int* __restrict__ gcur, long long* __restrict__ pcv,
        int* __restrict__ rs, int* __restrict__ re) {
    __shared__ long long ent[BWIN];       // 20.5 KB
    __shared__ int cnt[SUBROWS];
    __shared__ int off[SUBROWS];
    __shared__ int scanbuf[128];
    int s = blockIdx.x;
    int tid = threadIdx.x;
    int bb = s * BWIN;
    int n = gcur[s] - bb;

    for (int i = tid; i < n; i += 256) ent[i] = buf2[bb + i];
    for (int i = tid; i < SUBROWS; i += 256) cnt[i] = 0;
    __syncthreads();
    for (int i = tid; i < n; i += 256) {
        int rl = ((int)ent[i]) >> 18;
        atomicAdd(&cnt[rl], 1);
    }
    __syncthreads();
    int pc = 0;
    if (tid < 128) {
        int c = (tid < SUBROWS) ? cnt[tid] : 0;
        pc = (c + 15) & ~15;
        scanbuf[tid] = pc;
    }
    __syncthreads();
    for (int o = 1; o < 128; o <<= 1) {
        int x = 0;
        if (tid < 128 && tid >= o) x = scanbuf[tid - o];
        __syncthreads();
        if (tid < 128 && tid >= o) scanbuf[tid] += x;
        __syncthreads();
    }
    if (tid < SUBROWS) { off[tid] = scanbuf[tid] - pc; cnt[tid] = scanbuf[tid] - pc; }
    __syncthreads();
    long long* outp = pcv + (size_t)s * PSUB;
    for (int i = tid; i < n; i += 256) {
        long long e = ent[i];
        int rl = ((int)e) >> 18;
        int p = atomicAdd(&cnt[rl], 1);
        outp[p] = e;
    }
    __syncthreads();
    if (tid < SUBROWS) {
        int st = off[tid];
        int en = cnt[tid];
        int gend = st + ((en - st + 15) & ~15);
        for (int p = en; p < gend; ++p) outp[p] = 0;
        int gr = s * SUBROWS + tid;
        rs[gr] = s * PSUB + st;
        re[gr] = s * PSUB + gend;
    }
}

// ---------------- fused padded-CSR SpMM + elu + gated residual: h0 = gate*h0 - elu(L@t)
// pcv entries are wave-uniform -> scalar loads; 16 independent gathers in flight
__global__ __launch_bounds__(256) void spmm_csr_fused(const int* __restrict__ rs,
        const int* __restrict__ re, const long long* __restrict__ pcv,
        const unsigned short* __restrict__ tb,
        float* __restrict__ h0, const float* __restrict__ eps, int l) {
    int w = blockIdx.x * 4 + (threadIdx.x >> 6);
    int lane = threadIdx.x & 63;
    if (w >= NN) return;
    int s = rs[w], e = re[w];                // e-s is a multiple of 16
    float acc = 0.0f;
    for (int cb = s; cb < e; cb += 16) {
        long long pk[16];
        #pragma unroll
        for (int u = 0; u < 16; ++u) pk[u] = pcv[cb + u];   // uniform -> s_load
        float hv[16];
        #pragma unroll
        for (int u = 0; u < 16; ++u) {
            int c = ((int)pk[u]) & 0x3FFFF;
            hv[u] = __uint_as_float((unsigned)tb[(size_t)c * HC + lane] << 16);
        }
        #pragma unroll
        for (int u = 0; u < 16; ++u) {
            float v = __int_as_float((int)(pk[u] >> 32));
            acc = fmaf(v, hv[u], acc);
        }
    }
    float hnew = acc > 0.0f ? acc : expm1f(acc);
    int d = w % 3;
    float gate = 1.0f + tanhf(eps[l * 3 + d]);
    size_t idx = (size_t)w * HC + lane;
    float h0v = __builtin_nontemporal_load(h0 + idx);
    __builtin_nontemporal_store(gate * h0v - hnew, h0 + idx);
}

// ---------------- lin2 (tiled GEMM, N padded 40->64) + fused log_softmax
__global__ __launch_bounds__(256) void lin2_ls_gemm(const float* __restrict__ h,
        const float* __restrict__ W, const float* __restrict__ b,
        float* __restrict__ out) {
    const int K = 192;
    __shared__ float As[32][65];
    __shared__ float Bs[32][65];
    int tid = threadIdx.x;
    int tx = tid & 15, ty = tid >> 4;
    int m0 = blockIdx.x * 64;

    float acc[4][4] = {};
    int kslot = tid & 7;
    int row   = tid >> 3;

    for (int k0 = 0; k0 < K; k0 += 32) {
        #pragma unroll
        for (int pass = 0; pass < 2; ++pass) {
            int r = row + pass * 32;
            int gr = m0 + r;
            float4 v = make_float4(0.f, 0.f, 0.f, 0.f);
            if (gr < G_N) v = *(const float4*)(h + (size_t)gr * K + k0 + kslot * 4);
            As[kslot*4+0][r] = v.x; As[kslot*4+1][r] = v.y;
            As[kslot*4+2][r] = v.z; As[kslot*4+3][r] = v.w;

            int j = r;
            float4 w4 = make_float4(0.f, 0.f, 0.f, 0.f);
            if (j < OUT_DIM) w4 = *(const float4*)(W + (size_t)j * K + k0 + kslot * 4);
            Bs[kslot*4+0][j] = w4.x; Bs[kslot*4+1][j] = w4.y;
            Bs[kslot*4+2][j] = w4.z; Bs[kslot*4+3][j] = w4.w;
        }
        __syncthreads();
        #pragma unroll 8
        for (int k = 0; k < 32; ++k) {
            float4 a4 = *(const float4*)&As[k][ty*4];
            float4 b4 = *(const float4*)&Bs[k][tx*4];
            float av[4] = {a4.x, a4.y, a4.z, a4.w};
            float bv[4] = {b4.x, b4.y, b4.z, b4.w};
            #pragma unroll
            for (int i = 0; i < 4; ++i)
                #pragma unroll
                for (int j = 0; j < 4; ++j)
                    acc[i][j] = fmaf(av[i], bv[j], acc[i][j]);
        }
        __syncthreads();
    }

    bool validc = (tx < 10);
    float bi[4];
    #pragma unroll
    for (int j = 0; j < 4; ++j) bi[j] = validc ? b[tx*4+j] : 0.0f;

    #pragma unroll
    for (int i = 0; i < 4; ++i) {
        int gr = m0 + ty*4 + i;
        float v[4];
        float mymax = -INFINITY;
        #pragma unroll
        for (int j = 0; j < 4; ++j) {
            v[j] = acc[i][j] + bi[j];
            if (validc) mymax = fmaxf(mymax, v[j]);
        }
        #pragma unroll
        for (int off = 1; off < 16; off <<= 1) mymax = fmaxf(mymax, __shfl_xor(mymax, off));
        float s = 0.0f;
        if (validc) {
            #pragma unroll
            for (int j = 0; j < 4; ++j) s += expf(v[j] - mymax);
        }
        #pragma unroll
        for (int off = 1; off < 16; off <<= 1) s += __shfl_xor(s, off);
        float lse = mymax + logf(s);
        if (gr < G_N && validc) {
            float4 o = make_float4(v[0]-lse, v[1]-lse, v[2]-lse, v[3]-lse);
            *(float4*)(out + (size_t)gr * OUT_DIM + tx*4) = o;
        }
    }
}

extern "C" void kernel_launch(void* const* d_in, const int* in_sizes, int n_in,
                              void* d_out, int out_size, void* d_ws, size_t ws_size,
                              hipStream_t stream) {
    const float* x      = (const float*)d_in[0];
    const int*   rows   = (const int*)d_in[1];
    const int*   cols   = (const int*)d_in[2];
    const float* vals   = (const float*)d_in[3];
    const float* lin1_w = (const float*)d_in[4];
    const float* lin1_b = (const float*)d_in[5];
    const float* left_w = (const float*)d_in[6];
    const float* right_w= (const float*)d_in[7];
    const float* eps    = (const float*)d_in[8];
    const float* lin2_w = (const float*)d_in[9];
    const float* lin2_b = (const float*)d_in[10];
    float* out = (float*)d_out;

    size_t bufElems = (size_t)NN * HC;                     // 9.6M
    float* h0 = (float*)d_ws;                              // 38.4 MB
    unsigned short* tb = (unsigned short*)(h0 + bufElems); // 19.2 MB
    long long* pcv = (long long*)(tb + bufElems);          // NSB*PSUB*8 = 44.2 MB
    int* rs   = (int*)(pcv + (size_t)NSB * PSUB);          // 150016
    int* re   = rs + 150016;                               // 150016
    int* gcur = re + 150016;                               // NSB

    // buf2 aliases h0/tb region (fully consumed before lin1 writes h0)
    long long* buf2 = (long long*)d_ws;                    // NSB*BWIN*8 = 24.6 MB

    dim3 b256(256);

    // --- sub-bucketed build (reused by all 4 layers) ---
    init_cur_k<<<dim3((NSB + 255) / 256), b256, 0, stream>>>(gcur);
    scatterA_k<<<dim3(NBLK_SCAT), dim3(1024), 0, stream>>>(rows, cols, vals, gcur, buf2);
    sortB_k<<<dim3(NSB), b256, 0, stream>>>(buf2, gcur, pcv, rs, re);

    // --- lin1 -> h0 (MFMA bf16) ---
    lin1_mfma<<<dim3((G_N + 63) / 64), b256, 0, stream>>>(x, lin1_w, lin1_b, h0);

    for (int l = 0; l < NL; ++l) {
        transform_mfma<<<dim3((NN + 63) / 64), b256, 0, stream>>>(
            h0, left_w + l * 9, right_w + l * HC * HC, tb);
        spmm_csr_fused<<<dim3((NN + 3) / 4), b256, 0, stream>>>(
            rs, re, pcv, tb, h0, eps, l);
    }

    lin2_ls_gemm<<<dim3((G_N + 63) / 64), b256, 0, stream>>>(h0, lin2_w, lin2_b, out);
}

// Round 11
// 560.459 us; speedup vs baseline: 7.0725x; 1.0807x over previous
//
#include <hip/hip_runtime.h>
#include <math.h>

#define G_N 50000
#define D_S 3
#define HC 64
#define IN_DIM 256
#define OUT_DIM 40
#define NL 4
#define NNZV 2400000
#define NN (G_N * D_S)          // 150000
#define SUBROWS 125
#define NSB 1200                // NN / SUBROWS
#define CHUNK 16384
#define NBLK_SCAT 147           // ceil(NNZV / CHUNK)
#define BWIN 2560               // buf2 window per sub
#define PSUB 4608               // padded pcv window per sub

typedef __attribute__((ext_vector_type(8))) short bf16x8;
typedef __attribute__((ext_vector_type(8))) unsigned short u16x8;
typedef __attribute__((ext_vector_type(4))) float f32x4;

__device__ __forceinline__ float elu_f(float v) {
    return v > 0.0f ? v : expm1f(v);
}

__device__ __forceinline__ unsigned short f2bf(float f) {
    unsigned u = __float_as_uint(f);
    return (unsigned short)((u + 0x7FFF + ((u >> 16) & 1)) >> 16);
}

__device__ __forceinline__ float bf2f(unsigned short u) {
    return __uint_as_float((unsigned)u << 16);
}

// ---------------- lin1 via MFMA bf16: h0b[g,j] = bf16(elu(x@W1^T + b))
__global__ __launch_bounds__(256) void lin1_mfma(const float* __restrict__ x,
        const float* __restrict__ W, const float* __restrict__ b,
        unsigned short* __restrict__ h0b) {
    __shared__ __align__(16) unsigned short Ab[2][64][72];
    __shared__ __align__(16) unsigned short Bb[2][192][72];
    int tid = threadIdx.x;
    int m0 = blockIdx.x * 64;
    int w = tid >> 6, lane = tid & 63;
    int l15 = lane & 15, kg = lane >> 4;

    f32x4 acc[12];
    #pragma unroll
    for (int nb = 0; nb < 12; ++nb) acc[nb] = (f32x4){0.f, 0.f, 0.f, 0.f};

    auto stage = [&](int kt, int bf) {
        int k0 = kt * 64;
        #pragma unroll
        for (int p = 0; p < 4; ++p) {
            int fid = p * 256 + tid;
            int r = fid >> 4, kq = fid & 15;
            int gr = m0 + r;
            float4 v = make_float4(0.f, 0.f, 0.f, 0.f);
            if (gr < G_N) v = *(const float4*)(x + (size_t)gr * IN_DIM + k0 + kq * 4);
            Ab[bf][r][kq*4+0] = f2bf(v.x); Ab[bf][r][kq*4+1] = f2bf(v.y);
            Ab[bf][r][kq*4+2] = f2bf(v.z); Ab[bf][r][kq*4+3] = f2bf(v.w);
        }
        #pragma unroll
        for (int p = 0; p < 12; ++p) {
            int fid = p * 256 + tid;
            int j = fid >> 4, kq = fid & 15;
            float4 v = *(const float4*)(W + (size_t)j * IN_DIM + k0 + kq * 4);
            Bb[bf][j][kq*4+0] = f2bf(v.x); Bb[bf][j][kq*4+1] = f2bf(v.y);
            Bb[bf][j][kq*4+2] = f2bf(v.z); Bb[bf][j][kq*4+3] = f2bf(v.w);
        }
    };

    stage(0, 0);
    __syncthreads();
    int bf = 0;
    for (int kt = 0; kt < 4; ++kt) {
        if (kt < 3) stage(kt + 1, bf ^ 1);
        #pragma unroll
        for (int ks = 0; ks < 2; ++ks) {
            bf16x8 af = *(const bf16x8*)&Ab[bf][w*16 + l15][ks*32 + kg*8];
            #pragma unroll
            for (int nb = 0; nb < 12; ++nb) {
                bf16x8 bv = *(const bf16x8*)&Bb[bf][nb*16 + l15][ks*32 + kg*8];
                acc[nb] = __builtin_amdgcn_mfma_f32_16x16x32_bf16(af, bv, acc[nb], 0, 0, 0);
            }
        }
        __syncthreads();
        bf ^= 1;
    }

    // D layout: col = lane&15, row = (lane>>4)*4 + reg
    #pragma unroll
    for (int nb = 0; nb < 12; ++nb) {
        float bias = b[nb*16 + l15];
        #pragma unroll
        for (int i = 0; i < 4; ++i) {
            int gr = m0 + w*16 + kg*4 + i;
            if (gr < G_N)
                h0b[(size_t)gr * 192 + nb*16 + l15] = f2bf(elu_f(acc[nb][i] + bias));
        }
    }
}

// ---------------- transform via MFMA bf16: tb[n,j] = bf16(sum_c A[n,c]*Wr[j,c])
// A[g*3+e,c] = sum_d lw[e,d]*h0b[g*3+d,c]  (bf16 in, fp32 mix)
__global__ __launch_bounds__(256) void transform_mfma(const unsigned short* __restrict__ h0b,
        const float* __restrict__ lw, const float* __restrict__ Wr,
        unsigned short* __restrict__ tb) {
    __shared__ __align__(16) unsigned short Asb[64][72];
    __shared__ __align__(16) unsigned short Bsb[64][72];
    int tid = threadIdx.x;
    int r0 = blockIdx.x * 64;

    float L[9];
    #pragma unroll
    for (int i = 0; i < 9; ++i) L[i] = lw[i];

    #pragma unroll
    for (int p = 0; p < 16; ++p) {
        int idx = p * 256 + tid;
        Bsb[idx >> 6][idx & 63] = f2bf(Wr[idx]);
    }
    // stage A: 64 rows x 16 c-quads, vectorized ushort4 loads
    #pragma unroll
    for (int p = 0; p < 4; ++p) {
        int idx = p * 256 + tid;
        int r = idx >> 4, cq = idx & 15;
        int gr = r0 + r;
        ushort4 o = make_ushort4(0, 0, 0, 0);
        if (gr < NN) {
            int g = gr / 3, e = gr - g * 3;
            const unsigned short* base = h0b + (size_t)(g * 3) * HC + cq * 4;
            ushort4 a0 = *(const ushort4*)(base);
            ushort4 a1 = *(const ushort4*)(base + HC);
            ushort4 a2 = *(const ushort4*)(base + 2 * HC);
            float l0 = L[e*3+0], l1 = L[e*3+1], l2 = L[e*3+2];
            o.x = f2bf(l0*bf2f(a0.x) + l1*bf2f(a1.x) + l2*bf2f(a2.x));
            o.y = f2bf(l0*bf2f(a0.y) + l1*bf2f(a1.y) + l2*bf2f(a2.y));
            o.z = f2bf(l0*bf2f(a0.z) + l1*bf2f(a1.z) + l2*bf2f(a2.z));
            o.w = f2bf(l0*bf2f(a0.w) + l1*bf2f(a1.w) + l2*bf2f(a2.w));
        }
        *(ushort4*)&Asb[r][cq*4] = o;
    }
    __syncthreads();

    int w = tid >> 6, lane = tid & 63;
    int l15 = lane & 15, kg = lane >> 4;

    f32x4 acc[4];
    #pragma unroll
    for (int nb = 0; nb < 4; ++nb) acc[nb] = (f32x4){0.f, 0.f, 0.f, 0.f};

    #pragma unroll
    for (int ks = 0; ks < 2; ++ks) {
        bf16x8 af = *(const bf16x8*)&Asb[w*16 + l15][ks*32 + kg*8];
        #pragma unroll
        for (int nb = 0; nb < 4; ++nb) {
            bf16x8 bfv = *(const bf16x8*)&Bsb[nb*16 + l15][ks*32 + kg*8];
            acc[nb] = __builtin_amdgcn_mfma_f32_16x16x32_bf16(af, bfv, acc[nb], 0, 0, 0);
        }
    }

    #pragma unroll
    for (int nb = 0; nb < 4; ++nb) {
        #pragma unroll
        for (int i = 0; i < 4; ++i) {
            int rr = r0 + w*16 + kg*4 + i;
            if (rr < NN) tb[(size_t)rr * HC + nb*16 + l15] = f2bf(acc[nb][i]);
        }
    }
}

// ---------------- build step 0: init per-sub cursors to fixed windows
__global__ __launch_bounds__(256) void init_cur_k(int* __restrict__ gcur) {
    int i = blockIdx.x * 256 + threadIdx.x;
    if (i < NSB) gcur[i] = i * BWIN;
}

// ---------------- build step 1: partition COO into fixed per-sub windows (1024 thr)
__global__ __launch_bounds__(1024) void scatterA_k(const int* __restrict__ rows,
        const int* __restrict__ cols, const float* __restrict__ vals,
        int* __restrict__ gcur, long long* __restrict__ buf2) {
    __shared__ int cnt[NSB];
    __shared__ int base[NSB];
    int tid = threadIdx.x;
    for (int i = tid; i < NSB; i += 1024) cnt[i] = 0;
    __syncthreads();
    int c0 = blockIdx.x * CHUNK;
    #pragma unroll 4
    for (int it = 0; it < CHUNK / 1024; ++it) {
        int i = c0 + it * 1024 + tid;
        if (i < NNZV) atomicAdd(&cnt[rows[i] / SUBROWS], 1);
    }
    __syncthreads();
    for (int s = tid; s < NSB; s += 1024) {
        int c = cnt[s];
        if (c) base[s] = atomicAdd(&gcur[s], c);
        cnt[s] = 0;
    }
    __syncthreads();
    #pragma unroll 4
    for (int it = 0; it < CHUNK / 1024; ++it) {
        int i = c0 + it * 1024 + tid;
        if (i < NNZV) {
            int r = rows[i];
            int c = __builtin_nontemporal_load(cols + i);
            float v = __builtin_nontemporal_load(vals + i);
            int s = r / SUBROWS;
            int rloc = r - s * SUBROWS;
            int idx = atomicAdd(&cnt[s], 1);
            long long packed = ((long long)__float_as_int(v) << 32)
                             | (unsigned)((rloc << 18) | c);
            buf2[base[s] + idx] = packed;
        }
    }
}

// ---------------- build step 2: per-sub LDS sort -> row-contiguous padded CSR + rs/re
__global__ __launch_bounds__(256) void sortB_k(const long long* __restrict__ buf2,
        const int* __restrict__ gcur, long long* __restrict__ pcv,
        int* __restrict__ rs, int* __restrict__ re) {
    __shared__ long long ent[BWIN];
    __shared__ int cnt[SUBROWS];
    __shared__ int off[SUBROWS];
    __shared__ int scanbuf[128];
    int s = blockIdx.x;
    int tid = threadIdx.x;
    int bb = s * BWIN;
    int n = gcur[s] - bb;

    for (int i = tid; i < n; i += 256) ent[i] = buf2[bb + i];
    for (int i = tid; i < SUBROWS; i += 256) cnt[i] = 0;
    __syncthreads();
    for (int i = tid; i < n; i += 256) {
        int rl = ((int)ent[i]) >> 18;
        atomicAdd(&cnt[rl], 1);
    }
    __syncthreads();
    int pc = 0;
    if (tid < 128) {
        int c = (tid < SUBROWS) ? cnt[tid] : 0;
        pc = (c + 15) & ~15;
        scanbuf[tid] = pc;
    }
    __syncthreads();
    for (int o = 1; o < 128; o <<= 1) {
        int x = 0;
        if (tid < 128 && tid >= o) x = scanbuf[tid - o];
        __syncthreads();
        if (tid < 128 && tid >= o) scanbuf[tid] += x;
        __syncthreads();
    }
    if (tid < SUBROWS) { off[tid] = scanbuf[tid] - pc; cnt[tid] = scanbuf[tid] - pc; }
    __syncthreads();
    long long* outp = pcv + (size_t)s * PSUB;
    for (int i = tid; i < n; i += 256) {
        long long e = ent[i];
        int rl = ((int)e) >> 18;
        int p = atomicAdd(&cnt[rl], 1);
        outp[p] = e;
    }
    __syncthreads();
    if (tid < SUBROWS) {
        int st = off[tid];
        int en = cnt[tid];
        int gend = st + ((en - st + 15) & ~15);
        for (int p = en; p < gend; ++p) outp[p] = 0;
        int gr = s * SUBROWS + tid;
        rs[gr] = s * PSUB + st;
        re[gr] = s * PSUB + gend;
    }
}

// ---------------- fused padded-CSR SpMM + elu + gated residual (bf16 state):
// h0b = bf16( gate*h0b - elu(L@t) )
__global__ __launch_bounds__(256) void spmm_csr_fused(const int* __restrict__ rs,
        const int* __restrict__ re, const long long* __restrict__ pcv,
        const unsigned short* __restrict__ tb,
        unsigned short* __restrict__ h0b, const float* __restrict__ eps, int l) {
    int w = blockIdx.x * 4 + (threadIdx.x >> 6);
    int lane = threadIdx.x & 63;
    if (w >= NN) return;
    int s = rs[w], e = re[w];                // e-s is a multiple of 16
    float acc = 0.0f;
    for (int cb = s; cb < e; cb += 16) {
        long long pk[16];
        #pragma unroll
        for (int u = 0; u < 16; ++u) pk[u] = pcv[cb + u];   // uniform -> s_load
        float hv[16];
        #pragma unroll
        for (int u = 0; u < 16; ++u) {
            int c = ((int)pk[u]) & 0x3FFFF;
            hv[u] = bf2f(tb[(size_t)c * HC + lane]);
        }
        #pragma unroll
        for (int u = 0; u < 16; ++u) {
            float v = __int_as_float((int)(pk[u] >> 32));
            acc = fmaf(v, hv[u], acc);
        }
    }
    float hnew = acc > 0.0f ? acc : expm1f(acc);
    int d = w % 3;
    float gate = 1.0f + tanhf(eps[l * 3 + d]);
    size_t idx = (size_t)w * HC + lane;
    float h0v = bf2f(h0b[idx]);
    h0b[idx] = f2bf(gate * h0v - hnew);
}

// ---------------- lin2 (tiled GEMM over bf16 h, N padded 40->64) + fused log_softmax
__global__ __launch_bounds__(256) void lin2_ls_gemm(const unsigned short* __restrict__ h,
        const float* __restrict__ W, const float* __restrict__ b,
        float* __restrict__ out) {
    const int K = 192;
    __shared__ float As[32][65];
    __shared__ float Bs[32][65];
    int tid = threadIdx.x;
    int tx = tid & 15, ty = tid >> 4;
    int m0 = blockIdx.x * 64;

    float acc[4][4] = {};

    for (int k0 = 0; k0 < K; k0 += 32) {
        {   // A: 64 rows x 32 k, each thread one u16x8 (8 k)
            int r = tid >> 2, kb = (tid & 3) * 8;
            int gr = m0 + r;
            u16x8 v = (u16x8){0,0,0,0,0,0,0,0};
            if (gr < G_N) v = *(const u16x8*)(h + (size_t)gr * K + k0 + kb);
            #pragma unroll
            for (int j = 0; j < 8; ++j) As[kb + j][r] = bf2f(v[j]);
        }
        {   // B: 40 rows x 32 k fp32, two passes of float4
            int kslot = tid & 7, j = tid >> 3;
            #pragma unroll
            for (int pass = 0; pass < 2; ++pass) {
                int jj = j + pass * 32;
                float4 w4 = make_float4(0.f, 0.f, 0.f, 0.f);
                if (jj < OUT_DIM) w4 = *(const float4*)(W + (size_t)jj * K + k0 + kslot * 4);
                Bs[kslot*4+0][jj] = w4.x; Bs[kslot*4+1][jj] = w4.y;
                Bs[kslot*4+2][jj] = w4.z; Bs[kslot*4+3][jj] = w4.w;
            }
        }
        __syncthreads();
        #pragma unroll 8
        for (int k = 0; k < 32; ++k) {
            float4 a4 = *(const float4*)&As[k][ty*4];
            float4 b4 = *(const float4*)&Bs[k][tx*4];
            float av[4] = {a4.x, a4.y, a4.z, a4.w};
            float bv[4] = {b4.x, b4.y, b4.z, b4.w};
            #pragma unroll
            for (int i = 0; i < 4; ++i)
                #pragma unroll
                for (int j = 0; j < 4; ++j)
                    acc[i][j] = fmaf(av[i], bv[j], acc[i][j]);
        }
        __syncthreads();
    }

    bool validc = (tx < 10);
    float bi[4];
    #pragma unroll
    for (int j = 0; j < 4; ++j) bi[j] = validc ? b[tx*4+j] : 0.0f;

    #pragma unroll
    for (int i = 0; i < 4; ++i) {
        int gr = m0 + ty*4 + i;
        float v[4];
        float mymax = -INFINITY;
        #pragma unroll
        for (int j = 0; j < 4; ++j) {
            v[j] = acc[i][j] + bi[j];
            if (validc) mymax = fmaxf(mymax, v[j]);
        }
        #pragma unroll
        for (int off = 1; off < 16; off <<= 1) mymax = fmaxf(mymax, __shfl_xor(mymax, off));
        float s = 0.0f;
        if (validc) {
            #pragma unroll
            for (int j = 0; j < 4; ++j) s += expf(v[j] - mymax);
        }
        #pragma unroll
        for (int off = 1; off < 16; off <<= 1) s += __shfl_xor(s, off);
        float lse = mymax + logf(s);
        if (gr < G_N && validc) {
            float4 o = make_float4(v[0]-lse, v[1]-lse, v[2]-lse, v[3]-lse);
            *(float4*)(out + (size_t)gr * OUT_DIM + tx*4) = o;
        }
    }
}

extern "C" void kernel_launch(void* const* d_in, const int* in_sizes, int n_in,
                              void* d_out, int out_size, void* d_ws, size_t ws_size,
                              hipStream_t stream) {
    const float* x      = (const float*)d_in[0];
    const int*   rows   = (const int*)d_in[1];
    const int*   cols   = (const int*)d_in[2];
    const float* vals   = (const float*)d_in[3];
    const float* lin1_w = (const float*)d_in[4];
    const float* lin1_b = (const float*)d_in[5];
    const float* left_w = (const float*)d_in[6];
    const float* right_w= (const float*)d_in[7];
    const float* eps    = (const float*)d_in[8];
    const float* lin2_w = (const float*)d_in[9];
    const float* lin2_b = (const float*)d_in[10];
    float* out = (float*)d_out;

    size_t bufElems = (size_t)NN * HC;                       // 9.6M
    unsigned short* h0b = (unsigned short*)d_ws;             // 19.2 MB (bf16 state)
    unsigned short* tb  = h0b + bufElems;                    // 19.2 MB
    long long* pcv = (long long*)(tb + bufElems);            // NSB*PSUB*8 = 44.2 MB
    int* rs   = (int*)(pcv + (size_t)NSB * PSUB);            // 150016
    int* re   = rs + 150016;                                 // 150016
    int* gcur = re + 150016;                                 // NSB

    // buf2 aliases h0b+tb region (fully consumed by sortB before lin1 writes h0b)
    long long* buf2 = (long long*)d_ws;                      // NSB*BWIN*8 = 24.6 MB

    dim3 b256(256);

    // --- sub-bucketed build (reused by all 4 layers) ---
    init_cur_k<<<dim3((NSB + 255) / 256), b256, 0, stream>>>(gcur);
    scatterA_k<<<dim3(NBLK_SCAT), dim3(1024), 0, stream>>>(rows, cols, vals, gcur, buf2);
    sortB_k<<<dim3(NSB), b256, 0, stream>>>(buf2, gcur, pcv, rs, re);

    // --- lin1 -> h0b (MFMA bf16) ---
    lin1_mfma<<<dim3((G_N + 63) / 64), b256, 0, stream>>>(x, lin1_w, lin1_b, h0b);

    for (int l = 0; l < NL; ++l) {
        transform_mfma<<<dim3((NN + 63) / 64), b256, 0, stream>>>(
            h0b, left_w + l * 9, right_w + l * HC * HC, tb);
        spmm_csr_fused<<<dim3((NN + 3) / 4), b256, 0, stream>>>(
            rs, re, pcv, tb, h0b, eps, l);
    }

    lin2_ls_gemm<<<dim3((G_N + 63) / 64), b256, 0, stream>>>(h0b, lin2_w, lin2_b, out);
}

// Round 12
// 470.074 us; speedup vs baseline: 8.4324x; 1.1923x over previous
//
#include <hip/hip_runtime.h>
#include <math.h>

#define G_N 50000
#define D_S 3
#define HC 64
#define IN_DIM 256
#define OUT_DIM 40
#define NL 4
#define NNZV 2400000
#define NN (G_N * D_S)          // 150000
#define SUBROWS 125
#define NSB 1200                // NN / SUBROWS
#define CHUNK 16384
#define NBLK_SCAT 147           // ceil(NNZV / CHUNK)
#define BWIN 2560               // buf2 window per sub
#define PSUB 4608               // padded pcv window per sub

typedef __attribute__((ext_vector_type(8))) short bf16x8;
typedef __attribute__((ext_vector_type(8))) unsigned short u16x8;
typedef __attribute__((ext_vector_type(4))) float f32x4;

__device__ __forceinline__ float elu_f(float v) {
    return v > 0.0f ? v : expm1f(v);
}

__device__ __forceinline__ unsigned short f2bf(float f) {
    unsigned u = __float_as_uint(f);
    return (unsigned short)((u + 0x7FFF + ((u >> 16) & 1)) >> 16);
}

__device__ __forceinline__ float bf2f(unsigned short u) {
    return __uint_as_float((unsigned)u << 16);
}

// ---------------- lin1 via MFMA bf16: h0b[g,j] = bf16(elu(x@W1^T + b))
__global__ __launch_bounds__(256) void lin1_mfma(const float* __restrict__ x,
        const float* __restrict__ W, const float* __restrict__ b,
        unsigned short* __restrict__ h0b) {
    __shared__ __align__(16) unsigned short Ab[2][64][72];
    __shared__ __align__(16) unsigned short Bb[2][192][72];
    int tid = threadIdx.x;
    int m0 = blockIdx.x * 64;
    int w = tid >> 6, lane = tid & 63;
    int l15 = lane & 15, kg = lane >> 4;

    f32x4 acc[12];
    #pragma unroll
    for (int nb = 0; nb < 12; ++nb) acc[nb] = (f32x4){0.f, 0.f, 0.f, 0.f};

    auto stage = [&](int kt, int bf) {
        int k0 = kt * 64;
        #pragma unroll
        for (int p = 0; p < 4; ++p) {
            int fid = p * 256 + tid;
            int r = fid >> 4, kq = fid & 15;
            int gr = m0 + r;
            float4 v = make_float4(0.f, 0.f, 0.f, 0.f);
            if (gr < G_N) v = *(const float4*)(x + (size_t)gr * IN_DIM + k0 + kq * 4);
            Ab[bf][r][kq*4+0] = f2bf(v.x); Ab[bf][r][kq*4+1] = f2bf(v.y);
            Ab[bf][r][kq*4+2] = f2bf(v.z); Ab[bf][r][kq*4+3] = f2bf(v.w);
        }
        #pragma unroll
        for (int p = 0; p < 12; ++p) {
            int fid = p * 256 + tid;
            int j = fid >> 4, kq = fid & 15;
            float4 v = *(const float4*)(W + (size_t)j * IN_DIM + k0 + kq * 4);
            Bb[bf][j][kq*4+0] = f2bf(v.x); Bb[bf][j][kq*4+1] = f2bf(v.y);
            Bb[bf][j][kq*4+2] = f2bf(v.z); Bb[bf][j][kq*4+3] = f2bf(v.w);
        }
    };

    stage(0, 0);
    __syncthreads();
    int bf = 0;
    for (int kt = 0; kt < 4; ++kt) {
        if (kt < 3) stage(kt + 1, bf ^ 1);
        #pragma unroll
        for (int ks = 0; ks < 2; ++ks) {
            bf16x8 af = *(const bf16x8*)&Ab[bf][w*16 + l15][ks*32 + kg*8];
            #pragma unroll
            for (int nb = 0; nb < 12; ++nb) {
                bf16x8 bv = *(const bf16x8*)&Bb[bf][nb*16 + l15][ks*32 + kg*8];
                acc[nb] = __builtin_amdgcn_mfma_f32_16x16x32_bf16(af, bv, acc[nb], 0, 0, 0);
            }
        }
        __syncthreads();
        bf ^= 1;
    }

    // D layout: col = lane&15, row = (lane>>4)*4 + reg
    #pragma unroll
    for (int nb = 0; nb < 12; ++nb) {
        float bias = b[nb*16 + l15];
        #pragma unroll
        for (int i = 0; i < 4; ++i) {
            int gr = m0 + w*16 + kg*4 + i;
            if (gr < G_N)
                h0b[(size_t)gr * 192 + nb*16 + l15] = f2bf(elu_f(acc[nb][i] + bias));
        }
    }
}

// ---------------- transform via MFMA bf16: tb[n,j] = bf16(sum_c A[n,c]*Wr[j,c])
__global__ __launch_bounds__(256) void transform_mfma(const unsigned short* __restrict__ h0b,
        const float* __restrict__ lw, const float* __restrict__ Wr,
        unsigned short* __restrict__ tb) {
    __shared__ __align__(16) unsigned short Asb[64][72];
    __shared__ __align__(16) unsigned short Bsb[64][72];
    int tid = threadIdx.x;
    int r0 = blockIdx.x * 64;

    float L[9];
    #pragma unroll
    for (int i = 0; i < 9; ++i) L[i] = lw[i];

    #pragma unroll
    for (int p = 0; p < 16; ++p) {
        int idx = p * 256 + tid;
        Bsb[idx >> 6][idx & 63] = f2bf(Wr[idx]);
    }
    #pragma unroll
    for (int p = 0; p < 4; ++p) {
        int idx = p * 256 + tid;
        int r = idx >> 4, cq = idx & 15;
        int gr = r0 + r;
        ushort4 o = make_ushort4(0, 0, 0, 0);
        if (gr < NN) {
            int g = gr / 3, e = gr - g * 3;
            const unsigned short* base = h0b + (size_t)(g * 3) * HC + cq * 4;
            ushort4 a0 = *(const ushort4*)(base);
            ushort4 a1 = *(const ushort4*)(base + HC);
            ushort4 a2 = *(const ushort4*)(base + 2 * HC);
            float l0 = L[e*3+0], l1 = L[e*3+1], l2 = L[e*3+2];
            o.x = f2bf(l0*bf2f(a0.x) + l1*bf2f(a1.x) + l2*bf2f(a2.x));
            o.y = f2bf(l0*bf2f(a0.y) + l1*bf2f(a1.y) + l2*bf2f(a2.y));
            o.z = f2bf(l0*bf2f(a0.z) + l1*bf2f(a1.z) + l2*bf2f(a2.z));
            o.w = f2bf(l0*bf2f(a0.w) + l1*bf2f(a1.w) + l2*bf2f(a2.w));
        }
        *(ushort4*)&Asb[r][cq*4] = o;
    }
    __syncthreads();

    int w = tid >> 6, lane = tid & 63;
    int l15 = lane & 15, kg = lane >> 4;

    f32x4 acc[4];
    #pragma unroll
    for (int nb = 0; nb < 4; ++nb) acc[nb] = (f32x4){0.f, 0.f, 0.f, 0.f};

    #pragma unroll
    for (int ks = 0; ks < 2; ++ks) {
        bf16x8 af = *(const bf16x8*)&Asb[w*16 + l15][ks*32 + kg*8];
        #pragma unroll
        for (int nb = 0; nb < 4; ++nb) {
            bf16x8 bfv = *(const bf16x8*)&Bsb[nb*16 + l15][ks*32 + kg*8];
            acc[nb] = __builtin_amdgcn_mfma_f32_16x16x32_bf16(af, bfv, acc[nb], 0, 0, 0);
        }
    }

    #pragma unroll
    for (int nb = 0; nb < 4; ++nb) {
        #pragma unroll
        for (int i = 0; i < 4; ++i) {
            int rr = r0 + w*16 + kg*4 + i;
            if (rr < NN) tb[(size_t)rr * HC + nb*16 + l15] = f2bf(acc[nb][i]);
        }
    }
}

// ---------------- build step 0
__global__ __launch_bounds__(256) void init_cur_k(int* __restrict__ gcur) {
    int i = blockIdx.x * 256 + threadIdx.x;
    if (i < NSB) gcur[i] = i * BWIN;
}

// ---------------- build step 1: partition COO into fixed per-sub windows (1024 thr)
__global__ __launch_bounds__(1024) void scatterA_k(const int* __restrict__ rows,
        const int* __restrict__ cols, const float* __restrict__ vals,
        int* __restrict__ gcur, long long* __restrict__ buf2) {
    __shared__ int cnt[NSB];
    __shared__ int base[NSB];
    int tid = threadIdx.x;
    for (int i = tid; i < NSB; i += 1024) cnt[i] = 0;
    __syncthreads();
    int c0 = blockIdx.x * CHUNK;
    #pragma unroll 4
    for (int it = 0; it < CHUNK / 1024; ++it) {
        int i = c0 + it * 1024 + tid;
        if (i < NNZV) atomicAdd(&cnt[rows[i] / SUBROWS], 1);
    }
    __syncthreads();
    for (int s = tid; s < NSB; s += 1024) {
        int c = cnt[s];
        if (c) base[s] = atomicAdd(&gcur[s], c);
        cnt[s] = 0;
    }
    __syncthreads();
    #pragma unroll 4
    for (int it = 0; it < CHUNK / 1024; ++it) {
        int i = c0 + it * 1024 + tid;
        if (i < NNZV) {
            int r = rows[i];
            int c = __builtin_nontemporal_load(cols + i);
            float v = __builtin_nontemporal_load(vals + i);
            int s = r / SUBROWS;
            int rloc = r - s * SUBROWS;
            int idx = atomicAdd(&cnt[s], 1);
            long long packed = ((long long)__float_as_int(v) << 32)
                             | (unsigned)((rloc << 18) | c);
            buf2[base[s] + idx] = packed;
        }
    }
}

// ---------------- build step 2: per-sub LDS sort -> row-contiguous padded CSR + rs/re
__global__ __launch_bounds__(256) void sortB_k(const long long* __restrict__ buf2,
        const int* __restrict__ gcur, long long* __restrict__ pcv,
        int* __restrict__ rs, int* __restrict__ re) {
    __shared__ long long ent[BWIN];
    __shared__ int cnt[SUBROWS];
    __shared__ int off[SUBROWS];
    __shared__ int scanbuf[128];
    int s = blockIdx.x;
    int tid = threadIdx.x;
    int bb = s * BWIN;
    int n = gcur[s] - bb;

    for (int i = tid; i < n; i += 256) ent[i] = buf2[bb + i];
    for (int i = tid; i < SUBROWS; i += 256) cnt[i] = 0;
    __syncthreads();
    for (int i = tid; i < n; i += 256) {
        int rl = ((int)ent[i]) >> 18;
        atomicAdd(&cnt[rl], 1);
    }
    __syncthreads();
    int pc = 0;
    if (tid < 128) {
        int c = (tid < SUBROWS) ? cnt[tid] : 0;
        pc = (c + 15) & ~15;
        scanbuf[tid] = pc;
    }
    __syncthreads();
    for (int o = 1; o < 128; o <<= 1) {
        int x = 0;
        if (tid < 128 && tid >= o) x = scanbuf[tid - o];
        __syncthreads();
        if (tid < 128 && tid >= o) scanbuf[tid] += x;
        __syncthreads();
    }
    if (tid < SUBROWS) { off[tid] = scanbuf[tid] - pc; cnt[tid] = scanbuf[tid] - pc; }
    __syncthreads();
    long long* outp = pcv + (size_t)s * PSUB;
    for (int i = tid; i < n; i += 256) {
        long long e = ent[i];
        int rl = ((int)e) >> 18;
        int p = atomicAdd(&cnt[rl], 1);
        outp[p] = e;
    }
    __syncthreads();
    if (tid < SUBROWS) {
        int st = off[tid];
        int en = cnt[tid];
        int gend = st + ((en - st + 15) & ~15);
        for (int p = en; p < gend; ++p) outp[p] = 0;
        int gr = s * SUBROWS + tid;
        rs[gr] = s * PSUB + st;
        re[gr] = s * PSUB + gend;
    }
}

// ---------------- fused padded-CSR SpMM + elu + gated residual (bf16 state)
// rs/re hoisted to SGPR via readfirstlane -> pcv reads go to scalar path (s_load)
__global__ __launch_bounds__(256) void spmm_csr_fused(const int* __restrict__ rs,
        const int* __restrict__ re, const long long* __restrict__ pcv,
        const unsigned short* __restrict__ tb,
        unsigned short* __restrict__ h0b, const float* __restrict__ eps, int l) {
    int w = blockIdx.x * 4 + (threadIdx.x >> 6);
    int lane = threadIdx.x & 63;
    if (w >= NN) return;
    int s = __builtin_amdgcn_readfirstlane(rs[w]);
    int e = __builtin_amdgcn_readfirstlane(re[w]);   // e-s is a multiple of 16
    float acc = 0.0f;
    for (int cb = s; cb < e; cb += 16) {
        const long long* p = pcv + cb;               // uniform (SGPR) base
        long long pk[16];
        #pragma unroll
        for (int u = 0; u < 16; ++u) pk[u] = p[u];   // scalar s_load path
        float hv[16];
        #pragma unroll
        for (int u = 0; u < 16; ++u) {
            int c = ((int)pk[u]) & 0x3FFFF;          // scalar
            hv[u] = bf2f(tb[(size_t)c * HC + lane]); // saddr + lane voffset gather
        }
        #pragma unroll
        for (int u = 0; u < 16; ++u) {
            float v = __int_as_float((int)(pk[u] >> 32));
            acc = fmaf(v, hv[u], acc);
        }
    }
    float hnew = acc > 0.0f ? acc : expm1f(acc);
    int d = w % 3;
    float gate = 1.0f + tanhf(eps[l * 3 + d]);
    size_t idx = (size_t)w * HC + lane;
    float h0v = bf2f(h0b[idx]);
    h0b[idx] = f2bf(gate * h0v - hnew);
}

// ---------------- lin2 (tiled GEMM over bf16 h, N padded 40->64) + fused log_softmax
__global__ __launch_bounds__(256) void lin2_ls_gemm(const unsigned short* __restrict__ h,
        const float* __restrict__ W, const float* __restrict__ b,
        float* __restrict__ out) {
    const int K = 192;
    __shared__ float As[32][65];
    __shared__ float Bs[32][65];
    int tid = threadIdx.x;
    int tx = tid & 15, ty = tid >> 4;
    int m0 = blockIdx.x * 64;

    float acc[4][4] = {};

    for (int k0 = 0; k0 < K; k0 += 32) {
        {   // A: 64 rows x 32 k, each thread one u16x8 (8 k)
            int r = tid >> 2, kb = (tid & 3) * 8;
            int gr = m0 + r;
            u16x8 v = (u16x8){0,0,0,0,0,0,0,0};
            if (gr < G_N) v = *(const u16x8*)(h + (size_t)gr * K + k0 + kb);
            #pragma unroll
            for (int j = 0; j < 8; ++j) As[kb + j][r] = bf2f(v[j]);
        }
        {   // B: 40 rows x 32 k fp32, two passes of float4
            int kslot = tid & 7, j = tid >> 3;
            #pragma unroll
            for (int pass = 0; pass < 2; ++pass) {
                int jj = j + pass * 32;
                float4 w4 = make_float4(0.f, 0.f, 0.f, 0.f);
                if (jj < OUT_DIM) w4 = *(const float4*)(W + (size_t)jj * K + k0 + kslot * 4);
                Bs[kslot*4+0][jj] = w4.x; Bs[kslot*4+1][jj] = w4.y;
                Bs[kslot*4+2][jj] = w4.z; Bs[kslot*4+3][jj] = w4.w;
            }
        }
        __syncthreads();
        #pragma unroll 8
        for (int k = 0; k < 32; ++k) {
            float4 a4 = *(const float4*)&As[k][ty*4];
            float4 b4 = *(const float4*)&Bs[k][tx*4];
            float av[4] = {a4.x, a4.y, a4.z, a4.w};
            float bv[4] = {b4.x, b4.y, b4.z, b4.w};
            #pragma unroll
            for (int i = 0; i < 4; ++i)
                #pragma unroll
                for (int j = 0; j < 4; ++j)
                    acc[i][j] = fmaf(av[i], bv[j], acc[i][j]);
        }
        __syncthreads();
    }

    bool validc = (tx < 10);
    float bi[4];
    #pragma unroll
    for (int j = 0; j < 4; ++j) bi[j] = validc ? b[tx*4+j] : 0.0f;

    #pragma unroll
    for (int i = 0; i < 4; ++i) {
        int gr = m0 + ty*4 + i;
        float v[4];
        float mymax = -INFINITY;
        #pragma unroll
        for (int j = 0; j < 4; ++j) {
            v[j] = acc[i][j] + bi[j];
            if (validc) mymax = fmaxf(mymax, v[j]);
        }
        #pragma unroll
        for (int off = 1; off < 16; off <<= 1) mymax = fmaxf(mymax, __shfl_xor(mymax, off));
        float s = 0.0f;
        if (validc) {
            #pragma unroll
            for (int j = 0; j < 4; ++j) s += expf(v[j] - mymax);
        }
        #pragma unroll
        for (int off = 1; off < 16; off <<= 1) s += __shfl_xor(s, off);
        float lse = mymax + logf(s);
        if (gr < G_N && validc) {
            float4 o = make_float4(v[0]-lse, v[1]-lse, v[2]-lse, v[3]-lse);
            *(float4*)(out + (size_t)gr * OUT_DIM + tx*4) = o;
        }
    }
}

extern "C" void kernel_launch(void* const* d_in, const int* in_sizes, int n_in,
                              void* d_out, int out_size, void* d_ws, size_t ws_size,
                              hipStream_t stream) {
    const float* x      = (const float*)d_in[0];
    const int*   rows   = (const int*)d_in[1];
    const int*   cols   = (const int*)d_in[2];
    const float* vals   = (const float*)d_in[3];
    const float* lin1_w = (const float*)d_in[4];
    const float* lin1_b = (const float*)d_in[5];
    const float* left_w = (const float*)d_in[6];
    const float* right_w= (const float*)d_in[7];
    const float* eps    = (const float*)d_in[8];
    const float* lin2_w = (const float*)d_in[9];
    const float* lin2_b = (const float*)d_in[10];
    float* out = (float*)d_out;

    size_t bufElems = (size_t)NN * HC;                       // 9.6M
    unsigned short* h0b = (unsigned short*)d_ws;             // 19.2 MB (bf16 state)
    unsigned short* tb  = h0b + bufElems;                    // 19.2 MB
    long long* pcv = (long long*)(tb + bufElems);            // NSB*PSUB*8 = 44.2 MB
    int* rs   = (int*)(pcv + (size_t)NSB * PSUB);            // 150016
    int* re   = rs + 150016;                                 // 150016
    int* gcur = re + 150016;                                 // NSB

    // buf2 aliases h0b+tb region (fully consumed by sortB before lin1 writes h0b)
    long long* buf2 = (long long*)d_ws;                      // NSB*BWIN*8 = 24.6 MB

    dim3 b256(256);

    // --- sub-bucketed build (reused by all 4 layers) ---
    init_cur_k<<<dim3((NSB + 255) / 256), b256, 0, stream>>>(gcur);
    scatterA_k<<<dim3(NBLK_SCAT), dim3(1024), 0, stream>>>(rows, cols, vals, gcur, buf2);
    sortB_k<<<dim3(NSB), b256, 0, stream>>>(buf2, gcur, pcv, rs, re);

    // --- lin1 -> h0b (MFMA bf16) ---
    lin1_mfma<<<dim3((G_N + 63) / 64), b256, 0, stream>>>(x, lin1_w, lin1_b, h0b);

    for (int l = 0; l < NL; ++l) {
        transform_mfma<<<dim3((NN + 63) / 64), b256, 0, stream>>>(
            h0b, left_w + l * 9, right_w + l * HC * HC, tb);
        spmm_csr_fused<<<dim3((NN + 3) / 4), b256, 0, stream>>>(
            rs, re, pcv, tb, h0b, eps, l);
    }

    lin2_ls_gemm<<<dim3((G_N + 63) / 64), b256, 0, stream>>>(h0b, lin2_w, lin2_b, out);
}

// Round 13
// 461.755 us; speedup vs baseline: 8.5844x; 1.0180x over previous
//
#include <hip/hip_runtime.h>
#include <math.h>

#define G_N 50000
#define D_S 3
#define HC 64
#define IN_DIM 256
#define OUT_DIM 40
#define NL 4
#define NNZV 2400000
#define NN (G_N * D_S)          // 150000
#define SUBROWS 125
#define NSB 1200                // NN / SUBROWS
#define CHUNK 16384
#define NBLK_SCAT 147           // ceil(NNZV / CHUNK)
#define BWIN 2560               // buf2 window per sub
#define PSUB 4608               // padded pcv window per sub
#define W1_ELEMS (192 * IN_DIM)     // 49152
#define RW_ELEMS (NL * HC * HC)     // 16384

typedef __attribute__((ext_vector_type(8))) short bf16x8;
typedef __attribute__((ext_vector_type(8))) unsigned short u16x8;
typedef __attribute__((ext_vector_type(4))) float f32x4;

__device__ __forceinline__ float elu_f(float v) {
    return v > 0.0f ? v : expm1f(v);
}

__device__ __forceinline__ unsigned short f2bf(float f) {
    unsigned u = __float_as_uint(f);
    return (unsigned short)((u + 0x7FFF + ((u >> 16) & 1)) >> 16);
}

__device__ __forceinline__ float bf2f(unsigned short u) {
    return __uint_as_float((unsigned)u << 16);
}

// ---------------- one-shot weight conversion: lin1_w + right_w -> bf16
__global__ __launch_bounds__(256) void conv_w_k(const float* __restrict__ w1,
        const float* __restrict__ rw, unsigned short* __restrict__ w1b,
        unsigned short* __restrict__ rwb) {
    int i = blockIdx.x * 256 + threadIdx.x;
    if (i < W1_ELEMS) w1b[i] = f2bf(w1[i]);
    if (i < RW_ELEMS) rwb[i] = f2bf(rw[i]);
}

// ---------------- lin1 via MFMA bf16: h0b[g,j] = bf16(elu(x@W1^T + b))
// staging: A fp32->bf16 packed 8B stores; B pure bf16 16B copies
__global__ __launch_bounds__(256) void lin1_mfma(const float* __restrict__ x,
        const unsigned short* __restrict__ w1b, const float* __restrict__ b,
        unsigned short* __restrict__ h0b) {
    __shared__ __align__(16) unsigned short Ab[2][64][72];
    __shared__ __align__(16) unsigned short Bb[2][192][72];
    int tid = threadIdx.x;
    int m0 = blockIdx.x * 64;
    int w = tid >> 6, lane = tid & 63;
    int l15 = lane & 15, kg = lane >> 4;

    f32x4 acc[12];
    #pragma unroll
    for (int nb = 0; nb < 12; ++nb) acc[nb] = (f32x4){0.f, 0.f, 0.f, 0.f};

    auto stage = [&](int kt, int bf) {
        int k0 = kt * 64;
        // A: 64 rows x 64 k = 512 8-elem units, 2 per thread
        #pragma unroll
        for (int p = 0; p < 2; ++p) {
            int uid = p * 256 + tid;
            int r = uid >> 3, kq = uid & 7;
            int gr = m0 + r;
            ushort4 lo = make_ushort4(0, 0, 0, 0), hi = lo;
            if (gr < G_N) {
                const float* xp = x + (size_t)gr * IN_DIM + k0 + kq * 8;
                float4 v0 = *(const float4*)(xp);
                float4 v1 = *(const float4*)(xp + 4);
                lo.x = f2bf(v0.x); lo.y = f2bf(v0.y); lo.z = f2bf(v0.z); lo.w = f2bf(v0.w);
                hi.x = f2bf(v1.x); hi.y = f2bf(v1.y); hi.z = f2bf(v1.z); hi.w = f2bf(v1.w);
            }
            *(ushort4*)&Ab[bf][r][kq*8]     = lo;
            *(ushort4*)&Ab[bf][r][kq*8 + 4] = hi;
        }
        // B: 192 rows x 64 k = 1536 8-elem units, 6 per thread (pure copy)
        #pragma unroll
        for (int p = 0; p < 6; ++p) {
            int uid = p * 256 + tid;
            int j = uid >> 3, kq = uid & 7;
            u16x8 v = *(const u16x8*)(w1b + (size_t)j * IN_DIM + k0 + kq * 8);
            *(u16x8*)&Bb[bf][j][kq*8] = v;
        }
    };

    stage(0, 0);
    __syncthreads();
    int bf = 0;
    for (int kt = 0; kt < 4; ++kt) {
        if (kt < 3) stage(kt + 1, bf ^ 1);
        #pragma unroll
        for (int ks = 0; ks < 2; ++ks) {
            bf16x8 af = *(const bf16x8*)&Ab[bf][w*16 + l15][ks*32 + kg*8];
            #pragma unroll
            for (int nb = 0; nb < 12; ++nb) {
                bf16x8 bv = *(const bf16x8*)&Bb[bf][nb*16 + l15][ks*32 + kg*8];
                acc[nb] = __builtin_amdgcn_mfma_f32_16x16x32_bf16(af, bv, acc[nb], 0, 0, 0);
            }
        }
        __syncthreads();
        bf ^= 1;
    }

    // D layout: col = lane&15, row = (lane>>4)*4 + reg
    #pragma unroll
    for (int nb = 0; nb < 12; ++nb) {
        float bias = b[nb*16 + l15];
        #pragma unroll
        for (int i = 0; i < 4; ++i) {
            int gr = m0 + w*16 + kg*4 + i;
            if (gr < G_N)
                h0b[(size_t)gr * 192 + nb*16 + l15] = f2bf(elu_f(acc[nb][i] + bias));
        }
    }
}

// ---------------- transform via MFMA bf16: tb[n,j] = bf16(sum_c A[n,c]*Wr[j,c])
__global__ __launch_bounds__(256) void transform_mfma(const unsigned short* __restrict__ h0b,
        const float* __restrict__ lw, const unsigned short* __restrict__ Wrb,
        unsigned short* __restrict__ tb) {
    __shared__ __align__(16) unsigned short Asb[64][72];
    __shared__ __align__(16) unsigned short Bsb[64][72];
    int tid = threadIdx.x;
    int r0 = blockIdx.x * 64;

    float L[9];
    #pragma unroll
    for (int i = 0; i < 9; ++i) L[i] = lw[i];

    // B: 64x64 bf16 = 512 8-elem units, 2 per thread (pure copy)
    #pragma unroll
    for (int p = 0; p < 2; ++p) {
        int uid = p * 256 + tid;
        int j = uid >> 3, kq = uid & 7;
        u16x8 v = *(const u16x8*)(Wrb + (size_t)j * HC + kq * 8);
        *(u16x8*)&Bsb[j][kq*8] = v;
    }
    // A: left-mix in fp32, packed 8B stores
    #pragma unroll
    for (int p = 0; p < 4; ++p) {
        int idx = p * 256 + tid;
        int r = idx >> 4, cq = idx & 15;
        int gr = r0 + r;
        ushort4 o = make_ushort4(0, 0, 0, 0);
        if (gr < NN) {
            int g = gr / 3, e = gr - g * 3;
            const unsigned short* base = h0b + (size_t)(g * 3) * HC + cq * 4;
            ushort4 a0 = *(const ushort4*)(base);
            ushort4 a1 = *(const ushort4*)(base + HC);
            ushort4 a2 = *(const ushort4*)(base + 2 * HC);
            float l0 = L[e*3+0], l1 = L[e*3+1], l2 = L[e*3+2];
            o.x = f2bf(l0*bf2f(a0.x) + l1*bf2f(a1.x) + l2*bf2f(a2.x));
            o.y = f2bf(l0*bf2f(a0.y) + l1*bf2f(a1.y) + l2*bf2f(a2.y));
            o.z = f2bf(l0*bf2f(a0.z) + l1*bf2f(a1.z) + l2*bf2f(a2.z));
            o.w = f2bf(l0*bf2f(a0.w) + l1*bf2f(a1.w) + l2*bf2f(a2.w));
        }
        *(ushort4*)&Asb[r][cq*4] = o;
    }
    __syncthreads();

    int w = tid >> 6, lane = tid & 63;
    int l15 = lane & 15, kg = lane >> 4;

    f32x4 acc[4];
    #pragma unroll
    for (int nb = 0; nb < 4; ++nb) acc[nb] = (f32x4){0.f, 0.f, 0.f, 0.f};

    #pragma unroll
    for (int ks = 0; ks < 2; ++ks) {
        bf16x8 af = *(const bf16x8*)&Asb[w*16 + l15][ks*32 + kg*8];
        #pragma unroll
        for (int nb = 0; nb < 4; ++nb) {
            bf16x8 bfv = *(const bf16x8*)&Bsb[nb*16 + l15][ks*32 + kg*8];
            acc[nb] = __builtin_amdgcn_mfma_f32_16x16x32_bf16(af, bfv, acc[nb], 0, 0, 0);
        }
    }

    #pragma unroll
    for (int nb = 0; nb < 4; ++nb) {
        #pragma unroll
        for (int i = 0; i < 4; ++i) {
            int rr = r0 + w*16 + kg*4 + i;
            if (rr < NN) tb[(size_t)rr * HC + nb*16 + l15] = f2bf(acc[nb][i]);
        }
    }
}

// ---------------- build step 0
__global__ __launch_bounds__(256) void init_cur_k(int* __restrict__ gcur) {
    int i = blockIdx.x * 256 + threadIdx.x;
    if (i < NSB) gcur[i] = i * BWIN;
}

// ---------------- build step 1: partition COO into fixed per-sub windows (1024 thr)
__global__ __launch_bounds__(1024) void scatterA_k(const int* __restrict__ rows,
        const int* __restrict__ cols, const float* __restrict__ vals,
        int* __restrict__ gcur, long long* __restrict__ buf2) {
    __shared__ int cnt[NSB];
    __shared__ int base[NSB];
    int tid = threadIdx.x;
    for (int i = tid; i < NSB; i += 1024) cnt[i] = 0;
    __syncthreads();
    int c0 = blockIdx.x * CHUNK;
    #pragma unroll 4
    for (int it = 0; it < CHUNK / 1024; ++it) {
        int i = c0 + it * 1024 + tid;
        if (i < NNZV) atomicAdd(&cnt[rows[i] / SUBROWS], 1);
    }
    __syncthreads();
    for (int s = tid; s < NSB; s += 1024) {
        int c = cnt[s];
        if (c) base[s] = atomicAdd(&gcur[s], c);
        cnt[s] = 0;
    }
    __syncthreads();
    #pragma unroll 4
    for (int it = 0; it < CHUNK / 1024; ++it) {
        int i = c0 + it * 1024 + tid;
        if (i < NNZV) {
            int r = rows[i];
            int c = __builtin_nontemporal_load(cols + i);
            float v = __builtin_nontemporal_load(vals + i);
            int s = r / SUBROWS;
            int rloc = r - s * SUBROWS;
            int idx = atomicAdd(&cnt[s], 1);
            long long packed = ((long long)__float_as_int(v) << 32)
                             | (unsigned)((rloc << 18) | c);
            buf2[base[s] + idx] = packed;
        }
    }
}

// ---------------- build step 2: per-sub LDS sort -> row-contiguous padded CSR + rs/re
__global__ __launch_bounds__(256) void sortB_k(const long long* __restrict__ buf2,
        const int* __restrict__ gcur, long long* __restrict__ pcv,
        int* __restrict__ rs, int* __restrict__ re) {
    __shared__ long long ent[BWIN];
    __shared__ int cnt[SUBROWS];
    __shared__ int off[SUBROWS];
    __shared__ int scanbuf[128];
    int s = blockIdx.x;
    int tid = threadIdx.x;
    int bb = s * BWIN;
    int n = gcur[s] - bb;

    for (int i = tid; i < n; i += 256) ent[i] = buf2[bb + i];
    for (int i = tid; i < SUBROWS; i += 256) cnt[i] = 0;
    __syncthreads();
    for (int i = tid; i < n; i += 256) {
        int rl = ((int)ent[i]) >> 18;
        atomicAdd(&cnt[rl], 1);
    }
    __syncthreads();
    int pc = 0;
    if (tid < 128) {
        int c = (tid < SUBROWS) ? cnt[tid] : 0;
        pc = (c + 15) & ~15;
        scanbuf[tid] = pc;
    }
    __syncthreads();
    for (int o = 1; o < 128; o <<= 1) {
        int x = 0;
        if (tid < 128 && tid >= o) x = scanbuf[tid - o];
        __syncthreads();
        if (tid < 128 && tid >= o) scanbuf[tid] += x;
        __syncthreads();
    }
    if (tid < SUBROWS) { off[tid] = scanbuf[tid] - pc; cnt[tid] = scanbuf[tid] - pc; }
    __syncthreads();
    long long* outp = pcv + (size_t)s * PSUB;
    for (int i = tid; i < n; i += 256) {
        long long e = ent[i];
        int rl = ((int)e) >> 18;
        int p = atomicAdd(&cnt[rl], 1);
        outp[p] = e;
    }
    __syncthreads();
    if (tid < SUBROWS) {
        int st = off[tid];
        int en = cnt[tid];
        int gend = st + ((en - st + 15) & ~15);
        for (int p = en; p < gend; ++p) outp[p] = 0;
        int gr = s * SUBROWS + tid;
        rs[gr] = s * PSUB + st;
        re[gr] = s * PSUB + gend;
    }
}

// ---------------- fused padded-CSR SpMM + elu + gated residual (bf16 state)
// rs/re hoisted to SGPR via readfirstlane -> pcv reads go to scalar path (s_load)
__global__ __launch_bounds__(256) void spmm_csr_fused(const int* __restrict__ rs,
        const int* __restrict__ re, const long long* __restrict__ pcv,
        const unsigned short* __restrict__ tb,
        unsigned short* __restrict__ h0b, const float* __restrict__ eps, int l) {
    int w = blockIdx.x * 4 + (threadIdx.x >> 6);
    int lane = threadIdx.x & 63;
    if (w >= NN) return;
    int s = __builtin_amdgcn_readfirstlane(rs[w]);
    int e = __builtin_amdgcn_readfirstlane(re[w]);   // e-s is a multiple of 16
    float acc = 0.0f;
    for (int cb = s; cb < e; cb += 16) {
        const long long* p = pcv + cb;               // uniform (SGPR) base
        long long pk[16];
        #pragma unroll
        for (int u = 0; u < 16; ++u) pk[u] = p[u];   // scalar s_load path
        float hv[16];
        #pragma unroll
        for (int u = 0; u < 16; ++u) {
            int c = ((int)pk[u]) & 0x3FFFF;          // scalar
            hv[u] = bf2f(tb[(size_t)c * HC + lane]); // saddr + lane voffset gather
        }
        #pragma unroll
        for (int u = 0; u < 16; ++u) {
            float v = __int_as_float((int)(pk[u] >> 32));
            acc = fmaf(v, hv[u], acc);
        }
    }
    float hnew = acc > 0.0f ? acc : expm1f(acc);
    int d = w % 3;
    float gate = 1.0f + tanhf(eps[l * 3 + d]);
    size_t idx = (size_t)w * HC + lane;
    float h0v = bf2f(h0b[idx]);
    h0b[idx] = f2bf(gate * h0v - hnew);
}

// ---------------- lin2 (tiled GEMM over bf16 h, N padded 40->64) + fused log_softmax
__global__ __launch_bounds__(256) void lin2_ls_gemm(const unsigned short* __restrict__ h,
        const float* __restrict__ W, const float* __restrict__ b,
        float* __restrict__ out) {
    const int K = 192;
    __shared__ float As[32][65];
    __shared__ float Bs[32][65];
    int tid = threadIdx.x;
    int tx = tid & 15, ty = tid >> 4;
    int m0 = blockIdx.x * 64;

    float acc[4][4] = {};

    for (int k0 = 0; k0 < K; k0 += 32) {
        {   // A: 64 rows x 32 k, each thread one u16x8 (8 k)
            int r = tid >> 2, kb = (tid & 3) * 8;
            int gr = m0 + r;
            u16x8 v = (u16x8){0,0,0,0,0,0,0,0};
            if (gr < G_N) v = *(const u16x8*)(h + (size_t)gr * K + k0 + kb);
            #pragma unroll
            for (int j = 0; j < 8; ++j) As[kb + j][r] = bf2f(v[j]);
        }
        {   // B: 40 rows x 32 k fp32, two passes of float4
            int kslot = tid & 7, j = tid >> 3;
            #pragma unroll
            for (int pass = 0; pass < 2; ++pass) {
                int jj = j + pass * 32;
                float4 w4 = make_float4(0.f, 0.f, 0.f, 0.f);
                if (jj < OUT_DIM) w4 = *(const float4*)(W + (size_t)jj * K + k0 + kslot * 4);
                Bs[kslot*4+0][jj] = w4.x; Bs[kslot*4+1][jj] = w4.y;
                Bs[kslot*4+2][jj] = w4.z; Bs[kslot*4+3][jj] = w4.w;
            }
        }
        __syncthreads();
        #pragma unroll 8
        for (int k = 0; k < 32; ++k) {
            float4 a4 = *(const float4*)&As[k][ty*4];
            float4 b4 = *(const float4*)&Bs[k][tx*4];
            float av[4] = {a4.x, a4.y, a4.z, a4.w};
            float bv[4] = {b4.x, b4.y, b4.z, b4.w};
            #pragma unroll
            for (int i = 0; i < 4; ++i)
                #pragma unroll
                for (int j = 0; j < 4; ++j)
                    acc[i][j] = fmaf(av[i], bv[j], acc[i][j]);
        }
        __syncthreads();
    }

    bool validc = (tx < 10);
    float bi[4];
    #pragma unroll
    for (int j = 0; j < 4; ++j) bi[j] = validc ? b[tx*4+j] : 0.0f;

    #pragma unroll
    for (int i = 0; i < 4; ++i) {
        int gr = m0 + ty*4 + i;
        float v[4];
        float mymax = -INFINITY;
        #pragma unroll
        for (int j = 0; j < 4; ++j) {
            v[j] = acc[i][j] + bi[j];
            if (validc) mymax = fmaxf(mymax, v[j]);
        }
        #pragma unroll
        for (int off = 1; off < 16; off <<= 1) mymax = fmaxf(mymax, __shfl_xor(mymax, off));
        float s = 0.0f;
        if (validc) {
            #pragma unroll
            for (int j = 0; j < 4; ++j) s += expf(v[j] - mymax);
        }
        #pragma unroll
        for (int off = 1; off < 16; off <<= 1) s += __shfl_xor(s, off);
        float lse = mymax + logf(s);
        if (gr < G_N && validc) {
            float4 o = make_float4(v[0]-lse, v[1]-lse, v[2]-lse, v[3]-lse);
            *(float4*)(out + (size_t)gr * OUT_DIM + tx*4) = o;
        }
    }
}

extern "C" void kernel_launch(void* const* d_in, const int* in_sizes, int n_in,
                              void* d_out, int out_size, void* d_ws, size_t ws_size,
                              hipStream_t stream) {
    const float* x      = (const float*)d_in[0];
    const int*   rows   = (const int*)d_in[1];
    const int*   cols   = (const int*)d_in[2];
    const float* vals   = (const float*)d_in[3];
    const float* lin1_w = (const float*)d_in[4];
    const float* lin1_b = (const float*)d_in[5];
    const float* left_w = (const float*)d_in[6];
    const float* right_w= (const float*)d_in[7];
    const float* eps    = (const float*)d_in[8];
    const float* lin2_w = (const float*)d_in[9];
    const float* lin2_b = (const float*)d_in[10];
    float* out = (float*)d_out;

    size_t bufElems = (size_t)NN * HC;                       // 9.6M
    unsigned short* h0b = (unsigned short*)d_ws;             // 19.2 MB (bf16 state)
    unsigned short* tb  = h0b + bufElems;                    // 19.2 MB
    long long* pcv = (long long*)(tb + bufElems);            // NSB*PSUB*8 = 44.2 MB
    int* rs   = (int*)(pcv + (size_t)NSB * PSUB);            // 150016
    int* re   = rs + 150016;                                 // 150016
    int* gcur = re + 150016;                                 // NSB (1200) + pad to 1216
    unsigned short* w1b = (unsigned short*)(gcur + 1216);    // 49152 bf16
    unsigned short* rwb = w1b + W1_ELEMS;                    // 16384 bf16

    // buf2 aliases h0b+tb region (fully consumed by sortB before lin1 writes h0b)
    long long* buf2 = (long long*)d_ws;                      // NSB*BWIN*8 = 24.6 MB

    dim3 b256(256);

    // --- one-shot weight conversion + sub-bucketed build (reused by all 4 layers) ---
    conv_w_k<<<dim3((W1_ELEMS + 255) / 256), b256, 0, stream>>>(lin1_w, right_w, w1b, rwb);
    init_cur_k<<<dim3((NSB + 255) / 256), b256, 0, stream>>>(gcur);
    scatterA_k<<<dim3(NBLK_SCAT), dim3(1024), 0, stream>>>(rows, cols, vals, gcur, buf2);
    sortB_k<<<dim3(NSB), b256, 0, stream>>>(buf2, gcur, pcv, rs, re);

    // --- lin1 -> h0b (MFMA bf16) ---
    lin1_mfma<<<dim3((G_N + 63) / 64), b256, 0, stream>>>(x, w1b, lin1_b, h0b);

    for (int l = 0; l < NL; ++l) {
        transform_mfma<<<dim3((NN + 63) / 64), b256, 0, stream>>>(
            h0b, left_w + l * 9, rwb + l * HC * HC, tb);
        spmm_csr_fused<<<dim3((NN + 3) / 4), b256, 0, stream>>>(
            rs, re, pcv, tb, h0b, eps, l);
    }

    lin2_ls_gemm<<<dim3((G_N + 63) / 64), b256, 0, stream>>>(h0b, lin2_w, lin2_b, out);
}

// Round 14
// 454.730 us; speedup vs baseline: 8.7170x; 1.0154x over previous
//
#include <hip/hip_runtime.h>
#include <math.h>

#define G_N 50000
#define D_S 3
#define HC 64
#define IN_DIM 256
#define OUT_DIM 40
#define NL 4
#define NNZV 2400000
#define NN (G_N * D_S)          // 150000
#define SUBROWS 125
#define NSB 1200                // NN / SUBROWS
#define CHUNK 16384
#define NBLK_SCAT 147           // ceil(NNZV / CHUNK)
#define BWIN 2560               // buf2 window per sub
#define PSUB 4608               // padded pcv window per sub
#define W1_ELEMS (192 * IN_DIM)     // 49152
#define RW_ELEMS (NL * HC * HC)     // 16384

typedef __attribute__((ext_vector_type(8))) short bf16x8;
typedef __attribute__((ext_vector_type(8))) unsigned short u16x8;
typedef __attribute__((ext_vector_type(4))) float f32x4;

__device__ __forceinline__ float elu_f(float v) {
    return v > 0.0f ? v : expm1f(v);
}

__device__ __forceinline__ unsigned short f2bf(float f) {
    unsigned u = __float_as_uint(f);
    return (unsigned short)((u + 0x7FFF + ((u >> 16) & 1)) >> 16);
}

__device__ __forceinline__ float bf2f(unsigned short u) {
    return __uint_as_float((unsigned)u << 16);
}

// ---------------- one-shot weight conversion: lin1_w + right_w -> bf16
__global__ __launch_bounds__(256) void conv_w_k(const float* __restrict__ w1,
        const float* __restrict__ rw, unsigned short* __restrict__ w1b,
        unsigned short* __restrict__ rwb) {
    int i = blockIdx.x * 256 + threadIdx.x;
    if (i < W1_ELEMS) w1b[i] = f2bf(w1[i]);
    if (i < RW_ELEMS) rwb[i] = f2bf(rw[i]);
}

// ---------------- lin1 via MFMA bf16, barrier-free k-loop:
// B (96 cols x 256 k) staged once in LDS; A fragments loaded per-wave from global.
// block = 512 thr (8 waves) x 128 rows; grid.y = col half (0/1)
__global__ __launch_bounds__(512) void lin1_mfma(const float* __restrict__ x,
        const unsigned short* __restrict__ w1b, const float* __restrict__ b,
        unsigned short* __restrict__ h0b) {
    __shared__ __align__(16) unsigned short Bb[96][264];   // 50.7 KB
    int tid = threadIdx.x;
    int m0 = blockIdx.x * 128;
    int j0 = blockIdx.y * 96;
    int w = tid >> 6, lane = tid & 63;
    int l15 = lane & 15, kg = lane >> 4;

    // stage B once: 96 x 256 bf16 = 3072 u16x8 units, 6 per thread
    #pragma unroll
    for (int p = 0; p < 6; ++p) {
        int uid = p * 512 + tid;
        int j = uid >> 5, kq = uid & 31;
        u16x8 v = *(const u16x8*)(w1b + (size_t)(j0 + j) * IN_DIM + kq * 8);
        *(u16x8*)&Bb[j][kq*8] = v;
    }
    __syncthreads();

    int row = m0 + w * 16 + l15;          // this lane's A row
    const float* xp = x + (size_t)row * IN_DIM + kg * 8;
    bool rowok = (row < G_N);

    f32x4 acc[6];
    #pragma unroll
    for (int nb = 0; nb < 6; ++nb) acc[nb] = (f32x4){0.f, 0.f, 0.f, 0.f};

    #pragma unroll
    for (int kt = 0; kt < 8; ++kt) {      // 32 k per step, no barrier
        int k0 = kt * 32;
        ushort4 lo = make_ushort4(0,0,0,0), hi = lo;
        if (rowok) {
            float4 v0 = *(const float4*)(xp + k0);
            float4 v1 = *(const float4*)(xp + k0 + 4);
            lo.x = f2bf(v0.x); lo.y = f2bf(v0.y); lo.z = f2bf(v0.z); lo.w = f2bf(v0.w);
            hi.x = f2bf(v1.x); hi.y = f2bf(v1.y); hi.z = f2bf(v1.z); hi.w = f2bf(v1.w);
        }
        union { ushort4 u4[2]; bf16x8 bv; } af_u;
        af_u.u4[0] = lo; af_u.u4[1] = hi;
        bf16x8 af = af_u.bv;
        #pragma unroll
        for (int nb = 0; nb < 6; ++nb) {
            bf16x8 bfv = *(const bf16x8*)&Bb[nb*16 + l15][k0 + kg*8];
            acc[nb] = __builtin_amdgcn_mfma_f32_16x16x32_bf16(af, bfv, acc[nb], 0, 0, 0);
        }
    }

    // D layout: col = lane&15, row = (lane>>4)*4 + reg
    #pragma unroll
    for (int nb = 0; nb < 6; ++nb) {
        float bias = b[j0 + nb*16 + l15];
        #pragma unroll
        for (int i = 0; i < 4; ++i) {
            int gr = m0 + w*16 + kg*4 + i;
            if (gr < G_N)
                h0b[(size_t)gr * 192 + j0 + nb*16 + l15] = f2bf(elu_f(acc[nb][i] + bias));
        }
    }
}

// ---------------- transform via MFMA bf16: tb[n,j] = bf16(sum_c A[n,c]*Wr[j,c])
__global__ __launch_bounds__(256) void transform_mfma(const unsigned short* __restrict__ h0b,
        const float* __restrict__ lw, const unsigned short* __restrict__ Wrb,
        unsigned short* __restrict__ tb) {
    __shared__ __align__(16) unsigned short Asb[64][72];
    __shared__ __align__(16) unsigned short Bsb[64][72];
    int tid = threadIdx.x;
    int r0 = blockIdx.x * 64;

    float L[9];
    #pragma unroll
    for (int i = 0; i < 9; ++i) L[i] = lw[i];

    // B: 64x64 bf16 = 512 8-elem units, 2 per thread (pure copy)
    #pragma unroll
    for (int p = 0; p < 2; ++p) {
        int uid = p * 256 + tid;
        int j = uid >> 3, kq = uid & 7;
        u16x8 v = *(const u16x8*)(Wrb + (size_t)j * HC + kq * 8);
        *(u16x8*)&Bsb[j][kq*8] = v;
    }
    // A: left-mix in fp32, packed 8B stores
    #pragma unroll
    for (int p = 0; p < 4; ++p) {
        int idx = p * 256 + tid;
        int r = idx >> 4, cq = idx & 15;
        int gr = r0 + r;
        ushort4 o = make_ushort4(0, 0, 0, 0);
        if (gr < NN) {
            int g = gr / 3, e = gr - g * 3;
            const unsigned short* base = h0b + (size_t)(g * 3) * HC + cq * 4;
            ushort4 a0 = *(const ushort4*)(base);
            ushort4 a1 = *(const ushort4*)(base + HC);
            ushort4 a2 = *(const ushort4*)(base + 2 * HC);
            float l0 = L[e*3+0], l1 = L[e*3+1], l2 = L[e*3+2];
            o.x = f2bf(l0*bf2f(a0.x) + l1*bf2f(a1.x) + l2*bf2f(a2.x));
            o.y = f2bf(l0*bf2f(a0.y) + l1*bf2f(a1.y) + l2*bf2f(a2.y));
            o.z = f2bf(l0*bf2f(a0.z) + l1*bf2f(a1.z) + l2*bf2f(a2.z));
            o.w = f2bf(l0*bf2f(a0.w) + l1*bf2f(a1.w) + l2*bf2f(a2.w));
        }
        *(ushort4*)&Asb[r][cq*4] = o;
    }
    __syncthreads();

    int w = tid >> 6, lane = tid & 63;
    int l15 = lane & 15, kg = lane >> 4;

    f32x4 acc[4];
    #pragma unroll
    for (int nb = 0; nb < 4; ++nb) acc[nb] = (f32x4){0.f, 0.f, 0.f, 0.f};

    #pragma unroll
    for (int ks = 0; ks < 2; ++ks) {
        bf16x8 af = *(const bf16x8*)&Asb[w*16 + l15][ks*32 + kg*8];
        #pragma unroll
        for (int nb = 0; nb < 4; ++nb) {
            bf16x8 bfv = *(const bf16x8*)&Bsb[nb*16 + l15][ks*32 + kg*8];
            acc[nb] = __builtin_amdgcn_mfma_f32_16x16x32_bf16(af, bfv, acc[nb], 0, 0, 0);
        }
    }

    #pragma unroll
    for (int nb = 0; nb < 4; ++nb) {
        #pragma unroll
        for (int i = 0; i < 4; ++i) {
            int rr = r0 + w*16 + kg*4 + i;
            if (rr < NN) tb[(size_t)rr * HC + nb*16 + l15] = f2bf(acc[nb][i]);
        }
    }
}

// ---------------- build step 0
__global__ __launch_bounds__(256) void init_cur_k(int* __restrict__ gcur) {
    int i = blockIdx.x * 256 + threadIdx.x;
    if (i < NSB) gcur[i] = i * BWIN;
}

// ---------------- build step 1: partition COO into fixed per-sub windows (1024 thr)
__global__ __launch_bounds__(1024) void scatterA_k(const int* __restrict__ rows,
        const int* __restrict__ cols, const float* __restrict__ vals,
        int* __restrict__ gcur, long long* __restrict__ buf2) {
    __shared__ int cnt[NSB];
    __shared__ int base[NSB];
    int tid = threadIdx.x;
    for (int i = tid; i < NSB; i += 1024) cnt[i] = 0;
    __syncthreads();
    int c0 = blockIdx.x * CHUNK;
    #pragma unroll 4
    for (int it = 0; it < CHUNK / 1024; ++it) {
        int i = c0 + it * 1024 + tid;
        if (i < NNZV) atomicAdd(&cnt[rows[i] / SUBROWS], 1);
    }
    __syncthreads();
    for (int s = tid; s < NSB; s += 1024) {
        int c = cnt[s];
        if (c) base[s] = atomicAdd(&gcur[s], c);
        cnt[s] = 0;
    }
    __syncthreads();
    #pragma unroll 4
    for (int it = 0; it < CHUNK / 1024; ++it) {
        int i = c0 + it * 1024 + tid;
        if (i < NNZV) {
            int r = rows[i];
            int c = __builtin_nontemporal_load(cols + i);
            float v = __builtin_nontemporal_load(vals + i);
            int s = r / SUBROWS;
            int rloc = r - s * SUBROWS;
            int idx = atomicAdd(&cnt[s], 1);
            long long packed = ((long long)__float_as_int(v) << 32)
                             | (unsigned)((rloc << 18) | c);
            buf2[base[s] + idx] = packed;
        }
    }
}

// ---------------- build step 2: per-sub LDS sort -> row-contiguous padded CSR + rs/re
__global__ __launch_bounds__(256) void sortB_k(const long long* __restrict__ buf2,
        const int* __restrict__ gcur, long long* __restrict__ pcv,
        int* __restrict__ rs, int* __restrict__ re) {
    __shared__ long long ent[BWIN];
    __shared__ int cnt[SUBROWS];
    __shared__ int off[SUBROWS];
    __shared__ int scanbuf[128];
    int s = blockIdx.x;
    int tid = threadIdx.x;
    int bb = s * BWIN;
    int n = gcur[s] - bb;

    for (int i = tid; i < n; i += 256) ent[i] = buf2[bb + i];
    for (int i = tid; i < SUBROWS; i += 256) cnt[i] = 0;
    __syncthreads();
    for (int i = tid; i < n; i += 256) {
        int rl = ((int)ent[i]) >> 18;
        atomicAdd(&cnt[rl], 1);
    }
    __syncthreads();
    int pc = 0;
    if (tid < 128) {
        int c = (tid < SUBROWS) ? cnt[tid] : 0;
        pc = (c + 15) & ~15;
        scanbuf[tid] = pc;
    }
    __syncthreads();
    for (int o = 1; o < 128; o <<= 1) {
        int x = 0;
        if (tid < 128 && tid >= o) x = scanbuf[tid - o];
        __syncthreads();
        if (tid < 128 && tid >= o) scanbuf[tid] += x;
        __syncthreads();
    }
    if (tid < SUBROWS) { off[tid] = scanbuf[tid] - pc; cnt[tid] = scanbuf[tid] - pc; }
    __syncthreads();
    long long* outp = pcv + (size_t)s * PSUB;
    for (int i = tid; i < n; i += 256) {
        long long e = ent[i];
        int rl = ((int)e) >> 18;
        int p = atomicAdd(&cnt[rl], 1);
        outp[p] = e;
    }
    __syncthreads();
    if (tid < SUBROWS) {
        int st = off[tid];
        int en = cnt[tid];
        int gend = st + ((en - st + 15) & ~15);
        for (int p = en; p < gend; ++p) outp[p] = 0;
        int gr = s * SUBROWS + tid;
        rs[gr] = s * PSUB + st;
        re[gr] = s * PSUB + gend;
    }
}

// ---------------- fused padded-CSR SpMM + elu + gated residual (bf16 state)
// rs/re hoisted to SGPR via readfirstlane -> pcv reads go to scalar path (s_load)
__global__ __launch_bounds__(256) void spmm_csr_fused(const int* __restrict__ rs,
        const int* __restrict__ re, const long long* __restrict__ pcv,
        const unsigned short* __restrict__ tb,
        unsigned short* __restrict__ h0b, const float* __restrict__ eps, int l) {
    int w = blockIdx.x * 4 + (threadIdx.x >> 6);
    int lane = threadIdx.x & 63;
    if (w >= NN) return;
    int s = __builtin_amdgcn_readfirstlane(rs[w]);
    int e = __builtin_amdgcn_readfirstlane(re[w]);   // e-s is a multiple of 16
    float acc = 0.0f;
    for (int cb = s; cb < e; cb += 16) {
        const long long* p = pcv + cb;               // uniform (SGPR) base
        long long pk[16];
        #pragma unroll
        for (int u = 0; u < 16; ++u) pk[u] = p[u];   // scalar s_load path
        float hv[16];
        #pragma unroll
        for (int u = 0; u < 16; ++u) {
            int c = ((int)pk[u]) & 0x3FFFF;          // scalar
            hv[u] = bf2f(tb[(size_t)c * HC + lane]); // saddr + lane voffset gather
        }
        #pragma unroll
        for (int u = 0; u < 16; ++u) {
            float v = __int_as_float((int)(pk[u] >> 32));
            acc = fmaf(v, hv[u], acc);
        }
    }
    float hnew = acc > 0.0f ? acc : expm1f(acc);
    int d = w % 3;
    float gate = 1.0f + tanhf(eps[l * 3 + d]);
    size_t idx = (size_t)w * HC + lane;
    float h0v = bf2f(h0b[idx]);
    h0b[idx] = f2bf(gate * h0v - hnew);
}

// ---------------- lin2 (tiled GEMM over bf16 h, N padded 40->64) + fused log_softmax
__global__ __launch_bounds__(256) void lin2_ls_gemm(const unsigned short* __restrict__ h,
        const float* __restrict__ W, const float* __restrict__ b,
        float* __restrict__ out) {
    const int K = 192;
    __shared__ float As[32][65];
    __shared__ float Bs[32][65];
    int tid = threadIdx.x;
    int tx = tid & 15, ty = tid >> 4;
    int m0 = blockIdx.x * 64;

    float acc[4][4] = {};

    for (int k0 = 0; k0 < K; k0 += 32) {
        {   // A: 64 rows x 32 k, each thread one u16x8 (8 k)
            int r = tid >> 2, kb = (tid & 3) * 8;
            int gr = m0 + r;
            u16x8 v = (u16x8){0,0,0,0,0,0,0,0};
            if (gr < G_N) v = *(const u16x8*)(h + (size_t)gr * K + k0 + kb);
            #pragma unroll
            for (int j = 0; j < 8; ++j) As[kb + j][r] = bf2f(v[j]);
        }
        {   // B: 40 rows x 32 k fp32, two passes of float4
            int kslot = tid & 7, j = tid >> 3;
            #pragma unroll
            for (int pass = 0; pass < 2; ++pass) {
                int jj = j + pass * 32;
                float4 w4 = make_float4(0.f, 0.f, 0.f, 0.f);
                if (jj < OUT_DIM) w4 = *(const float4*)(W + (size_t)jj * K + k0 + kslot * 4);
                Bs[kslot*4+0][jj] = w4.x; Bs[kslot*4+1][jj] = w4.y;
                Bs[kslot*4+2][jj] = w4.z; Bs[kslot*4+3][jj] = w4.w;
            }
        }
        __syncthreads();
        #pragma unroll 8
        for (int k = 0; k < 32; ++k) {
            float4 a4 = *(const float4*)&As[k][ty*4];
            float4 b4 = *(const float4*)&Bs[k][tx*4];
            float av[4] = {a4.x, a4.y, a4.z, a4.w};
            float bv[4] = {b4.x, b4.y, b4.z, b4.w};
            #pragma unroll
            for (int i = 0; i < 4; ++i)
                #pragma unroll
                for (int j = 0; j < 4; ++j)
                    acc[i][j] = fmaf(av[i], bv[j], acc[i][j]);
        }
        __syncthreads();
    }

    bool validc = (tx < 10);
    float bi[4];
    #pragma unroll
    for (int j = 0; j < 4; ++j) bi[j] = validc ? b[tx*4+j] : 0.0f;

    #pragma unroll
    for (int i = 0; i < 4; ++i) {
        int gr = m0 + ty*4 + i;
        float v[4];
        float mymax = -INFINITY;
        #pragma unroll
        for (int j = 0; j < 4; ++j) {
            v[j] = acc[i][j] + bi[j];
            if (validc) mymax = fmaxf(mymax, v[j]);
        }
        #pragma unroll
        for (int off = 1; off < 16; off <<= 1) mymax = fmaxf(mymax, __shfl_xor(mymax, off));
        float s = 0.0f;
        if (validc) {
            #pragma unroll
            for (int j = 0; j < 4; ++j) s += expf(v[j] - mymax);
        }
        #pragma unroll
        for (int off = 1; off < 16; off <<= 1) s += __shfl_xor(s, off);
        float lse = mymax + logf(s);
        if (gr < G_N && validc) {
            float4 o = make_float4(v[0]-lse, v[1]-lse, v[2]-lse, v[3]-lse);
            *(float4*)(out + (size_t)gr * OUT_DIM + tx*4) = o;
        }
    }
}

extern "C" void kernel_launch(void* const* d_in, const int* in_sizes, int n_in,
                              void* d_out, int out_size, void* d_ws, size_t ws_size,
                              hipStream_t stream) {
    const float* x      = (const float*)d_in[0];
    const int*   rows   = (const int*)d_in[1];
    const int*   cols   = (const int*)d_in[2];
    const float* vals   = (const float*)d_in[3];
    const float* lin1_w = (const float*)d_in[4];
    const float* lin1_b = (const float*)d_in[5];
    const float* left_w = (const float*)d_in[6];
    const float* right_w= (const float*)d_in[7];
    const float* eps    = (const float*)d_in[8];
    const float* lin2_w = (const float*)d_in[9];
    const float* lin2_b = (const float*)d_in[10];
    float* out = (float*)d_out;

    size_t bufElems = (size_t)NN * HC;                       // 9.6M
    unsigned short* h0b = (unsigned short*)d_ws;             // 19.2 MB (bf16 state)
    unsigned short* tb  = h0b + bufElems;                    // 19.2 MB
    long long* pcv = (long long*)(tb + bufElems);            // NSB*PSUB*8 = 44.2 MB
    int* rs   = (int*)(pcv + (size_t)NSB * PSUB);            // 150016
    int* re   = rs + 150016;                                 // 150016
    int* gcur = re + 150016;                                 // NSB (1200) + pad to 1216
    unsigned short* w1b = (unsigned short*)(gcur + 1216);    // 49152 bf16
    unsigned short* rwb = w1b + W1_ELEMS;                    // 16384 bf16

    // buf2 aliases h0b+tb region (fully consumed by sortB before lin1 writes h0b)
    long long* buf2 = (long long*)d_ws;                      // NSB*BWIN*8 = 24.6 MB

    dim3 b256(256);

    // --- one-shot weight conversion + sub-bucketed build (reused by all 4 layers) ---
    conv_w_k<<<dim3((W1_ELEMS + 255) / 256), b256, 0, stream>>>(lin1_w, right_w, w1b, rwb);
    init_cur_k<<<dim3((NSB + 255) / 256), b256, 0, stream>>>(gcur);
    scatterA_k<<<dim3(NBLK_SCAT), dim3(1024), 0, stream>>>(rows, cols, vals, gcur, buf2);
    sortB_k<<<dim3(NSB), b256, 0, stream>>>(buf2, gcur, pcv, rs, re);

    // --- lin1 -> h0b (MFMA bf16, barrier-free) ---
    lin1_mfma<<<dim3((G_N + 127) / 128, 2), dim3(512), 0, stream>>>(x, w1b, lin1_b, h0b);

    for (int l = 0; l < NL; ++l) {
        transform_mfma<<<dim3((NN + 63) / 64), b256, 0, stream>>>(
            h0b, left_w + l * 9, rwb + l * HC * HC, tb);
        spmm_csr_fused<<<dim3((NN + 3) / 4), b256, 0, stream>>>(
            rs, re, pcv, tb, h0b, eps, l);
    }

    lin2_ls_gemm<<<dim3((G_N + 63) / 64), b256, 0, stream>>>(h0b, lin2_w, lin2_b, out);
}